// Round 5
// baseline (311.733 us; speedup 1.0000x reference)
//
#include <hip/hip_runtime.h>
#include <hip/hip_bf16.h>
#include <math.h>

#define NDOM 6
#define BB 4
#define TT 1024
#define DD 768
#define PP 3
#define HH 2
#define DHH 32
#define II 64
#define SS (PP*TT)        // 3072
#define NROW (NDOM*BB*TT) // 24576
#define NKVROW (NDOM*BB*SS)
#define NSPLIT 4
#define LNEPS 1e-5f

typedef unsigned int uint;
typedef uint  u32x4  __attribute__((ext_vector_type(4)));
typedef int   i32x2  __attribute__((ext_vector_type(2)));
typedef float f32x2  __attribute__((ext_vector_type(2)));
typedef float f32x4  __attribute__((ext_vector_type(4)));
typedef float f32x16 __attribute__((ext_vector_type(16)));
typedef __bf16 bf16x8 __attribute__((ext_vector_type(8)));

// D = A(32x16) * B(16x32) + C.  A row = lane&31, k = (lane>>5)*8+j.
// B col = lane&31, k = (lane>>5)*8+j.  D: col = lane&31, row=(r&3)+8*(r>>2)+4*(lane>>5).
__device__ __forceinline__ f32x16 mfma32(u32x4 a, u32x4 b, f32x16 c) {
  return __builtin_amdgcn_mfma_f32_32x32x16_bf16(
      __builtin_bit_cast(bf16x8, a), __builtin_bit_cast(bf16x8, b), c, 0, 0, 0);
}

__device__ __forceinline__ uint pkbf(float a, float b) {
  union { __bf16 h[2]; uint u; } v;
  v.h[0] = (__bf16)a; v.h[1] = (__bf16)b;
  return v.u;
}
__device__ __forceinline__ float b2f(uint u16) {
  union { uint i; float f; } v; v.i = u16 << 16; return v.f;
}

// x gets {a_lo | partner's b}, y gets {partner's a | b}  (32-lane halves)
__device__ __forceinline__ void plswap(uint a, uint b, uint& x, uint& y) {
#if __has_builtin(__builtin_amdgcn_permlane32_swap)
  i32x2 r = __builtin_amdgcn_permlane32_swap((int)a, (int)b, false, false);
  x = (uint)r.x; y = (uint)r.y;
#else
  uint sa = __shfl_xor(a, 32), sb = __shfl_xor(b, 32);
  bool h1 = (threadIdx.x & 32) != 0;
  x = h1 ? sb : a;
  y = h1 ? b : sa;
#endif
}

// ---------------------------------------------------------------------------
// Prep: bf16 transposed weights + exp2-domain mask bias.
// ---------------------------------------------------------------------------
__global__ __launch_bounds__(256) void prep_kernel(
    const int* __restrict__ mask, const float* __restrict__ Wk,
    const float* __restrict__ Wv, const float* __restrict__ Wq,
    const float* __restrict__ Wo,
    __hip_bfloat16* __restrict__ Bkv, __hip_bfloat16* __restrict__ Bq,
    __hip_bfloat16* __restrict__ Bo, float* __restrict__ bias2)
{
  int i = blockIdx.x * 256 + threadIdx.x;
  const int N1 = 128 * 768;          // Bkv
  const int N2 = NDOM * 64 * 768;    // Bq
  const int N3 = NDOM * 768 * 64;    // Bo
  if (i < N1) {
    int c = i / 768, k = i % 768;
    float v = (c < 64) ? Wk[k * 64 + c] : Wv[k * 64 + (c - 64)];
    Bkv[i] = __float2bfloat16(v);
  } else if (i < N1 + N2) {
    int j = i - N1;
    int n = j / (64 * 768);
    int rem = j % (64 * 768);
    int c = rem / 768, k = rem % 768;
    Bq[j] = __float2bfloat16(Wq[((size_t)n * 768 + k) * 64 + c]);
  } else if (i < N1 + N2 + N3) {
    int j = i - N1 - N2;
    int n = j / (768 * 64);
    int rem = j % (768 * 64);
    int d = rem / 64, k = rem % 64;
    Bo[j] = __float2bfloat16(Wo[((size_t)n * 64 + k) * 768 + d]);
  } else if (i < N1 + N2 + N3 + BB * SS) {
    int j = i - N1 - N2 - N3;
    int b = j / SS, s = j % SS;
    bias2[j] = (1.0f - (float)mask[b * TT + (s & (TT - 1))]) * (-14426.950408889634f);
  }
}

// ---------------------------------------------------------------------------
// Fused Q + KV projection GEMM, LDS-free.  Block = 4 waves; each wave owns a
// 32-row tile, loads its A fragments straight from global (f32x4 x2 per step,
// the two hi-halves jointly consume full 64B lines), cvt_pk in-register.
// Blocks [0,576): history rows -> K (row-major) + V (transposed Vt[c][s]).
// Blocks [576,768): x rows -> Q.
// ---------------------------------------------------------------------------
struct KvSt { f32x4 a0, a1; u32x4 b0, b1, b2, b3; };
struct QSt  { f32x4 a0, a1; u32x4 b0, b1; };

__global__ __launch_bounds__(256) void qkv_gemm_kernel(
    const float* __restrict__ x, const float* __restrict__ hist,
    const __hip_bfloat16* __restrict__ Bkv, const __hip_bfloat16* __restrict__ Bq,
    __hip_bfloat16* __restrict__ Qo, __hip_bfloat16* __restrict__ Kb,
    __hip_bfloat16* __restrict__ Vtb)
{
  const int tid = threadIdx.x;
  const int lane = tid & 63, w = tid >> 6;
  const int cl = lane & 31, hi = lane >> 5;

  if (blockIdx.x < NKVROW / 128) {
    // ---- KV part ----
    const int brow = blockIdx.x * 128;
    const int nb = brow / SS;
    const int n = nb >> 2, b = nb & 3;
    const int s0 = brow % SS;
    const int p = s0 / TT, t0 = s0 % TT;
    const int sw = s0 + w * 32;                 // s within nb, wave tile base
    const float* Ar = hist + (((size_t)(p * NDOM + n) * BB + b) * TT + t0 + w * 32 + cl) * 768;
    const __hip_bfloat16* Bb = Bkv + (size_t)cl * 768;

    f32x16 k0 = {}, k1 = {}, v0 = {}, v1 = {};

    auto load = [&](int s) {
      KvSt t;
      int k = s * 16 + hi * 8;
      t.a0 = *(const f32x4*)(Ar + k);
      t.a1 = *(const f32x4*)(Ar + k + 4);
      t.b0 = *(const u32x4*)(Bb + k);
      t.b1 = *(const u32x4*)(Bb + 32 * 768 + k);
      t.b2 = *(const u32x4*)(Bb + 64 * 768 + k);
      t.b3 = *(const u32x4*)(Bb + 96 * 768 + k);
      return t;
    };
    KvSt cur = load(0);
#pragma unroll 1
    for (int s = 0; s < 48; ++s) {
      KvSt nxt = load(s + 1 < 48 ? s + 1 : 47);
      u32x4 af = {pkbf(cur.a0.x, cur.a0.y), pkbf(cur.a0.z, cur.a0.w),
                  pkbf(cur.a1.x, cur.a1.y), pkbf(cur.a1.z, cur.a1.w)};
      k0 = mfma32(af, cur.b0, k0);
      k1 = mfma32(af, cur.b1, k1);
      v0 = mfma32(af, cur.b2, v0);
      v1 = mfma32(af, cur.b3, v1);
      cur = nxt;
    }
    // K store (row-major [s][64])
#pragma unroll
    for (int r = 0; r < 16; ++r) {
      int rl = (r & 3) + 8 * (r >> 2) + 4 * hi;
      size_t rb = (size_t)(brow + w * 32 + rl) * 64;
      Kb[rb + cl]      = __float2bfloat16(k0[r]);
      Kb[rb + 32 + cl] = __float2bfloat16(k1[r]);
    }
    // V store (transposed Vt[nb][c][3072])
#pragma unroll
    for (int g = 0; g < 4; ++g) {
      int sv = sw + 8 * g + 4 * hi;
      *(uint2*)(Vtb + ((size_t)nb * 64 + cl) * SS + sv) =
          uint2{pkbf(v0[4*g], v0[4*g+1]), pkbf(v0[4*g+2], v0[4*g+3])};
      *(uint2*)(Vtb + ((size_t)nb * 64 + 32 + cl) * SS + sv) =
          uint2{pkbf(v1[4*g], v1[4*g+1]), pkbf(v1[4*g+2], v1[4*g+3])};
    }
  } else {
    // ---- Q part ----
    const int qb = blockIdx.x - NKVROW / 128;
    const int grow = qb * 128 + w * 32;
    const int n = grow >> 12;
    const float* Ar = x + (size_t)(grow + cl) * 768;
    const __hip_bfloat16* Bb = Bq + (size_t)n * 64 * 768 + (size_t)cl * 768;

    f32x16 q0 = {}, q1 = {};
    auto load = [&](int s) {
      QSt t;
      int k = s * 16 + hi * 8;
      t.a0 = *(const f32x4*)(Ar + k);
      t.a1 = *(const f32x4*)(Ar + k + 4);
      t.b0 = *(const u32x4*)(Bb + k);
      t.b1 = *(const u32x4*)(Bb + 32 * 768 + k);
      return t;
    };
    QSt cur = load(0);
#pragma unroll 1
    for (int s = 0; s < 48; ++s) {
      QSt nxt = load(s + 1 < 48 ? s + 1 : 47);
      u32x4 af = {pkbf(cur.a0.x, cur.a0.y), pkbf(cur.a0.z, cur.a0.w),
                  pkbf(cur.a1.x, cur.a1.y), pkbf(cur.a1.z, cur.a1.w)};
      q0 = mfma32(af, cur.b0, q0);
      q1 = mfma32(af, cur.b1, q1);
      cur = nxt;
    }
#pragma unroll
    for (int r = 0; r < 16; ++r) {
      int rl = (r & 3) + 8 * (r >> 2) + 4 * hi;
      size_t rb = (size_t)(grow + rl) * 64;
      Qo[rb + cl]      = __float2bfloat16(q0[r]);
      Qo[rb + 32 + cl] = __float2bfloat16(q1[r]);
    }
  }
}

// ---------------------------------------------------------------------------
// Flash attention, split-S by 4.  1 wave = 32 queries, 768 keys, 64 keys/iter.
// Swapped QK^T; O^T accum; exp2-domain online softmax (f32x2-packed) with
// defer-max; permlane32_swap P repack.  bf16 partials + (m,l) to workspace.
// ---------------------------------------------------------------------------
struct KV { u32x4 k0, k1, k2, k3, v0, v1, v2, v3; };

__global__ __launch_bounds__(64) void attn_kernel(
    const __hip_bfloat16* __restrict__ Q, const __hip_bfloat16* __restrict__ K,
    const __hip_bfloat16* __restrict__ Vt, const float* __restrict__ bias2,
    __hip_bfloat16* __restrict__ Op, float* __restrict__ Mp, float* __restrict__ Lp)
{
  const int lane = threadIdx.x;
  const int cl = lane & 31, hi = lane >> 5;
  const int bid = blockIdx.x;
  const int g = bid % 48;            // (n,b,h) group -> fixed XCD (48 % 8 == 0)
  const int rest = bid / 48;         // 0..127
  const int sp = rest >> 5;          // split 0..3
  const int tile = rest & 31;        // q tile 0..31
  const int h = g & 1, nb = g >> 1;
  const int b = nb & 3;
  const int qrow = nb * TT + tile * 32;
  const int sbase = sp * (SS / NSPLIT);   // 768 keys per split

  const __hip_bfloat16* Qp = Q + (size_t)(qrow + cl) * 64 + h * 32 + hi * 8;
  u32x4 qf0 = *(const u32x4*)Qp;
  u32x4 qf1 = *(const u32x4*)(Qp + 16);

  const __hip_bfloat16* Kp = K + ((size_t)nb * SS + sbase + cl) * 64 + h * 32 + hi * 8;
  const __hip_bfloat16* Vp = Vt + ((size_t)nb * 64 + h * 32 + cl) * SS + sbase + hi * 8;
  const float* Bp = bias2 + b * SS + sbase + hi * 4;

  const float scale2 = 0.17677669529663687f * 1.4426950408889634f;
  const f32x2 sc2 = {scale2, scale2};

  f32x16 ot = {};
  float m = -1e30f, lsum = 0.f;

  auto loadKV = [&](int it) {
    KV t;
    const __hip_bfloat16* kp = Kp + (size_t)it * 64 * 64;
    t.k0 = *(const u32x4*)kp;
    t.k1 = *(const u32x4*)(kp + 16);
    t.k2 = *(const u32x4*)(kp + 32 * 64);
    t.k3 = *(const u32x4*)(kp + 32 * 64 + 16);
    const __hip_bfloat16* vp = Vp + it * 64;
    t.v0 = *(const u32x4*)vp;
    t.v1 = *(const u32x4*)(vp + 16);
    t.v2 = *(const u32x4*)(vp + 32);
    t.v3 = *(const u32x4*)(vp + 48);
    return t;
  };

  auto compute = [&](const KV& t, int it) {
    f32x16 pz0 = {}, pz1 = {};
    pz0 = mfma32(t.k0, qf0, pz0);
    pz0 = mfma32(t.k1, qf1, pz0);
    pz1 = mfma32(t.k2, qf0, pz1);
    pz1 = mfma32(t.k3, qf1, pz1);
    const float* bp = Bp + it * 64;
    f32x4 b4[8];
#pragma unroll
    for (int q = 0; q < 8; ++q) b4[q] = *(const f32x4*)(bp + 8 * q);
    f32x2 p2[16];
#pragma unroll
    for (int i = 0; i < 8; ++i) {
      f32x4 bq0 = b4[i >> 1];
      f32x4 bq1 = b4[4 + (i >> 1)];
      f32x2 bv0 = (i & 1) ? f32x2{bq0.z, bq0.w} : f32x2{bq0.x, bq0.y};
      f32x2 bv1 = (i & 1) ? f32x2{bq1.z, bq1.w} : f32x2{bq1.x, bq1.y};
      p2[i]     = f32x2{pz0[2*i], pz0[2*i+1]} * sc2 + bv0;
      p2[8 + i] = f32x2{pz1[2*i], pz1[2*i+1]} * sc2 + bv1;
    }
    f32x2 mx = p2[0];
#pragma unroll
    for (int i = 1; i < 16; ++i) {
      mx.x = fmaxf(mx.x, p2[i].x);
      mx.y = fmaxf(mx.y, p2[i].y);
    }
    float tm = fmaxf(mx.x, mx.y);
    tm = fmaxf(tm, __shfl_xor(tm, 32));
    if (!__all(tm - m <= 8.f)) {       // defer-max
      float mn = fmaxf(m, tm);
      float f = exp2f(m - mn);
#pragma unroll
      for (int i = 0; i < 16; ++i) ot[i] *= f;
      lsum *= f;
      m = mn;
    }
    const f32x2 m2 = {m, m};
    f32x2 s2 = {0.f, 0.f};
#pragma unroll
    for (int i = 0; i < 16; ++i) {
      f32x2 d = p2[i] - m2;
      f32x2 e = {exp2f(d.x), exp2f(d.y)};
      p2[i] = e;
      s2 += e;
    }
    float ts = s2.x + s2.y;
    ts += __shfl_xor(ts, 32);
    lsum += ts;
    // P -> bf16 B-frags via permlane32_swap
    uint cv[16];
#pragma unroll
    for (int i = 0; i < 16; ++i) cv[i] = pkbf(p2[i].x, p2[i].y);
    u32x4 pf0, pf1, pf2, pf3;
    {
      uint x0, y0, x1, y1;
      plswap(cv[0], cv[2],  x0, y0); plswap(cv[1], cv[3],  x1, y1);
      pf0 = u32x4{x0, x1, y0, y1};
      plswap(cv[4], cv[6],  x0, y0); plswap(cv[5], cv[7],  x1, y1);
      pf1 = u32x4{x0, x1, y0, y1};
      plswap(cv[8], cv[10], x0, y0); plswap(cv[9], cv[11], x1, y1);
      pf2 = u32x4{x0, x1, y0, y1};
      plswap(cv[12], cv[14], x0, y0); plswap(cv[13], cv[15], x1, y1);
      pf3 = u32x4{x0, x1, y0, y1};
    }
    ot = mfma32(t.v0, pf0, ot);
    ot = mfma32(t.v1, pf1, ot);
    ot = mfma32(t.v2, pf2, ot);
    ot = mfma32(t.v3, pf3, ot);
  };

  KV cur = loadKV(0);
#pragma unroll 1
  for (int it = 0; it < 12; ++it) {
    KV nxt = loadKV(it + 1 < 12 ? it + 1 : 11);
    compute(cur, it);
    cur = nxt;
  }

  // store unnormalized O^T partial (bf16) + m/l
  __hip_bfloat16* op = Op + ((size_t)sp * NROW + qrow + cl) * 64 + h * 32 + 4 * hi;
#pragma unroll
  for (int k = 0; k < 4; ++k) {
    uint2 wv = {pkbf(ot[4*k], ot[4*k+1]), pkbf(ot[4*k+2], ot[4*k+3])};
    *(uint2*)(op + 8 * k) = wv;
  }
  if (lane < 32) {
    int mi = ((sp * 24 + nb) * 2 + h) * TT + tile * 32 + cl;
    Mp[mi] = m;
    Lp[mi] = lsum;
  }
}

// ---------------------------------------------------------------------------
// Fused split-combine + out-projection (MFMA) + residual + LayerNorm.
// Block 256 = 4 waves, 32 rows; wave w owns cols [w*192, +192).
// Each wave combines the 4 attention partials in-register into its A-frags.
// ---------------------------------------------------------------------------
__global__ __launch_bounds__(256) void oproj_ln_kernel(
    const float* __restrict__ x, const __hip_bfloat16* __restrict__ Op,
    const float* __restrict__ Mp, const float* __restrict__ Lp,
    const __hip_bfloat16* __restrict__ Bo, const float* __restrict__ gamma,
    const float* __restrict__ beta, float* __restrict__ out)
{
  __shared__ float red[4][32][2];
  __shared__ float redf[32][2];
  const int tid = threadIdx.x;
  const int lane = tid & 63, w = tid >> 6;
  const int cl = lane & 31, hi = lane >> 5;
  const int row0 = blockIdx.x * 32;
  const int n = row0 >> 12;
  const int nb = row0 >> 10;
  const int trow = (row0 & 1023) + cl;
  const int MLS = 24 * 2 * TT;

  // combine weights per head
  float wsp[2][NSPLIT];
#pragma unroll
  for (int h = 0; h < 2; ++h) {
    int mi = (nb * 2 + h) * TT + trow;
    float mv[NSPLIT], lv[NSPLIT];
#pragma unroll
    for (int sp = 0; sp < NSPLIT; ++sp) { mv[sp] = Mp[mi + sp * MLS]; lv[sp] = Lp[mi + sp * MLS]; }
    float ms = mv[0];
#pragma unroll
    for (int sp = 1; sp < NSPLIT; ++sp) ms = fmaxf(ms, mv[sp]);
    float den = 0.f;
#pragma unroll
    for (int sp = 0; sp < NSPLIT; ++sp) { wsp[h][sp] = exp2f(mv[sp] - ms); den = fmaf(lv[sp], wsp[h][sp], den); }
    float inv = 1.0f / den;
#pragma unroll
    for (int sp = 0; sp < NSPLIT; ++sp) wsp[h][sp] *= inv;
  }

  // A-frags: combine partials
  u32x4 af[4];
#pragma unroll
  for (int ks = 0; ks < 4; ++ks) {
    int h = ks >> 1;
    size_t off = (size_t)(row0 + cl) * 64 + ks * 16 + hi * 8;
    f32x2 s0 = {}, s1 = {}, s2 = {}, s3 = {};
#pragma unroll
    for (int sp = 0; sp < NSPLIT; ++sp) {
      u32x4 v = *(const u32x4*)(Op + (size_t)sp * NROW * 64 + off);
      float wv = wsp[h][sp];
      s0 += f32x2{b2f(v[0] & 0xffffu), b2f(v[0] >> 16)} * wv;
      s1 += f32x2{b2f(v[1] & 0xffffu), b2f(v[1] >> 16)} * wv;
      s2 += f32x2{b2f(v[2] & 0xffffu), b2f(v[2] >> 16)} * wv;
      s3 += f32x2{b2f(v[3] & 0xffffu), b2f(v[3] >> 16)} * wv;
    }
    af[ks] = u32x4{pkbf(s0.x, s0.y), pkbf(s1.x, s1.y), pkbf(s2.x, s2.y), pkbf(s3.x, s3.y)};
  }

  const __hip_bfloat16* Bp = Bo + ((size_t)n * 768 + w * 192 + cl) * 64 + hi * 8;
  f32x16 acc[6] = {};
#pragma unroll
  for (int ks = 0; ks < 4; ++ks) {
#pragma unroll
    for (int t = 0; t < 6; ++t) {
      u32x4 bb = *(const u32x4*)(Bp + (size_t)(t * 32) * 64 + ks * 16);
      acc[t] = mfma32(af[ks], bb, acc[t]);
    }
  }

  float s1[16], s2[16];
#pragma unroll
  for (int r = 0; r < 16; ++r) { s1[r] = 0.f; s2[r] = 0.f; }
#pragma unroll
  for (int t = 0; t < 6; ++t) {
#pragma unroll
    for (int r = 0; r < 16; ++r) {
      int R = (r & 3) + 8 * (r >> 2) + 4 * hi;
      int col = w * 192 + t * 32 + cl;
      float y = acc[t][r] + x[(size_t)(row0 + R) * 768 + col];
      acc[t][r] = y;
      s1[r] += y;
      s2[r] = fmaf(y, y, s2[r]);
    }
  }
#pragma unroll
  for (int r = 0; r < 16; ++r) {
#pragma unroll
    for (int off = 1; off < 32; off <<= 1) {
      s1[r] += __shfl_xor(s1[r], off);
      s2[r] += __shfl_xor(s2[r], off);
    }
  }
  if (cl == 0) {
#pragma unroll
    for (int r = 0; r < 16; ++r) {
      int R = (r & 3) + 8 * (r >> 2) + 4 * hi;
      red[w][R][0] = s1[r];
      red[w][R][1] = s2[r];
    }
  }
  __syncthreads();
  if (tid < 64) {
    int R = tid & 31, st = tid >> 5;
    redf[R][st] = red[0][R][st] + red[1][R][st] + red[2][R][st] + red[3][R][st];
  }
  __syncthreads();

  float gv[6], bv[6];
#pragma unroll
  for (int t = 0; t < 6; ++t) {
    int col = w * 192 + t * 32 + cl;
    gv[t] = gamma[n * 768 + col];
    bv[t] = beta[n * 768 + col];
  }
#pragma unroll
  for (int r = 0; r < 16; ++r) {
    int R = (r & 3) + 8 * (r >> 2) + 4 * hi;
    float mu = redf[R][0] * (1.0f / 768.0f);
    float var = redf[R][1] * (1.0f / 768.0f) - mu * mu;
    float rs = rsqrtf(var + LNEPS);
#pragma unroll
    for (int t = 0; t < 6; ++t) {
      int col = w * 192 + t * 32 + cl;
      out[(size_t)(row0 + R) * 768 + col] = (acc[t][r] - mu) * rs * gv[t] + bv[t];
    }
  }
}

// ---------------------------------------------------------------------------
extern "C" void kernel_launch(void* const* d_in, const int* in_sizes, int n_in,
                              void* d_out, int out_size, void* d_ws, size_t ws_size,
                              hipStream_t stream) {
  const float* x     = (const float*)d_in[0];
  const float* hist  = (const float*)d_in[1];
  const int*   mask  = (const int*)d_in[2];
  const float* Wq    = (const float*)d_in[3];
  const float* Wk    = (const float*)d_in[4];
  const float* Wv    = (const float*)d_in[5];
  const float* Wo    = (const float*)d_in[6];
  const float* gamma = (const float*)d_in[7];
  const float* beta  = (const float*)d_in[8];
  float* out = (float*)d_out;

  char* ws = (char*)d_ws;
  __hip_bfloat16* Qb  = (__hip_bfloat16*)ws;  ws += (size_t)NROW * II * 2;
  __hip_bfloat16* Kb  = (__hip_bfloat16*)ws;  ws += (size_t)NKVROW * II * 2;
  __hip_bfloat16* Vtb = (__hip_bfloat16*)ws;  ws += (size_t)NDOM*BB*II * SS * 2;
  __hip_bfloat16* Op  = (__hip_bfloat16*)ws;  ws += (size_t)NSPLIT * NROW * II * 2;
  float* Mp           = (float*)ws;           ws += (size_t)NSPLIT * 24 * 2 * TT * 4;
  float* Lp           = (float*)ws;           ws += (size_t)NSPLIT * 24 * 2 * TT * 4;
  __hip_bfloat16* Bkv = (__hip_bfloat16*)ws;  ws += (size_t)128 * 768 * 2;
  __hip_bfloat16* Bq  = (__hip_bfloat16*)ws;  ws += (size_t)NDOM * 64 * 768 * 2;
  __hip_bfloat16* Bo  = (__hip_bfloat16*)ws;  ws += (size_t)NDOM * 768 * 64 * 2;
  float* bias2        = (float*)ws;           ws += (size_t)BB * SS * 4;

  const int PREP_N = 128*768 + NDOM*64*768 + NDOM*768*64 + BB*SS;
  prep_kernel<<<(PREP_N + 255) / 256, 256, 0, stream>>>(mask, Wk, Wv, Wq, Wo, Bkv, Bq, Bo, bias2);
  qkv_gemm_kernel<<<NKVROW / 128 + NROW / 128, 256, 0, stream>>>(x, hist, Bkv, Bq, Qb, Kb, Vtb);
  attn_kernel<<<48 * 32 * NSPLIT, 64, 0, stream>>>(Qb, Kb, Vtb, bias2, Op, Mp, Lp);
  oproj_ln_kernel<<<NROW / 32, 256, 0, stream>>>(x, Op, Mp, Lp, Bo, gamma, beta, out);
}

// Round 6
// 253.842 us; speedup vs baseline: 1.2281x; 1.2281x over previous
//
#include <hip/hip_runtime.h>
#include <hip/hip_bf16.h>
#include <math.h>

#define NDOM 6
#define BB 4
#define TT 1024
#define DD 768
#define PP 3
#define HH 2
#define DHH 32
#define II 64
#define SS (PP*TT)        // 3072
#define NROW (NDOM*BB*TT) // 24576
#define NKVROW (NDOM*BB*SS)
#define NSPLIT 4
#define LNEPS 1e-5f

typedef unsigned int uint;
typedef uint  u32x4  __attribute__((ext_vector_type(4)));
typedef int   i32x2  __attribute__((ext_vector_type(2)));
typedef float f32x2  __attribute__((ext_vector_type(2)));
typedef float f32x4  __attribute__((ext_vector_type(4)));
typedef float f32x16 __attribute__((ext_vector_type(16)));
typedef __bf16 bf16x8 __attribute__((ext_vector_type(8)));

// D = A(32x16) * B(16x32) + C.  A row = lane&31, k = (lane>>5)*8+j.
// B col = lane&31, k = (lane>>5)*8+j.  D: col = lane&31, row=(r&3)+8*(r>>2)+4*(lane>>5).
__device__ __forceinline__ f32x16 mfma32(u32x4 a, u32x4 b, f32x16 c) {
  return __builtin_amdgcn_mfma_f32_32x32x16_bf16(
      __builtin_bit_cast(bf16x8, a), __builtin_bit_cast(bf16x8, b), c, 0, 0, 0);
}

__device__ __forceinline__ uint pkbf(float a, float b) {
  union { __bf16 h[2]; uint u; } v;
  v.h[0] = (__bf16)a; v.h[1] = (__bf16)b;
  return v.u;
}
__device__ __forceinline__ float b2f(uint u16) {
  union { uint i; float f; } v; v.i = u16 << 16; return v.f;
}

// x gets {a_lo | partner's b}, y gets {partner's a | b}  (32-lane halves)
__device__ __forceinline__ void plswap(uint a, uint b, uint& x, uint& y) {
#if __has_builtin(__builtin_amdgcn_permlane32_swap)
  i32x2 r = __builtin_amdgcn_permlane32_swap((int)a, (int)b, false, false);
  x = (uint)r.x; y = (uint)r.y;
#else
  uint sa = __shfl_xor(a, 32), sb = __shfl_xor(b, 32);
  bool h1 = (threadIdx.x & 32) != 0;
  x = h1 ? sb : a;
  y = h1 ? b : sa;
#endif
}

// ---------------------------------------------------------------------------
// Prep: bf16 transposed weights + exp2-domain mask bias.
// ---------------------------------------------------------------------------
__global__ __launch_bounds__(256) void prep_kernel(
    const int* __restrict__ mask, const float* __restrict__ Wk,
    const float* __restrict__ Wv, const float* __restrict__ Wq,
    const float* __restrict__ Wo,
    __hip_bfloat16* __restrict__ Bkv, __hip_bfloat16* __restrict__ Bq,
    __hip_bfloat16* __restrict__ Bo, float* __restrict__ bias2)
{
  int i = blockIdx.x * 256 + threadIdx.x;
  const int N1 = 128 * 768;          // Bkv
  const int N2 = NDOM * 64 * 768;    // Bq
  const int N3 = NDOM * 768 * 64;    // Bo
  if (i < N1) {
    int c = i / 768, k = i % 768;
    float v = (c < 64) ? Wk[k * 64 + c] : Wv[k * 64 + (c - 64)];
    Bkv[i] = __float2bfloat16(v);
  } else if (i < N1 + N2) {
    int j = i - N1;
    int n = j / (64 * 768);
    int rem = j % (64 * 768);
    int c = rem / 768, k = rem % 768;
    Bq[j] = __float2bfloat16(Wq[((size_t)n * 768 + k) * 64 + c]);
  } else if (i < N1 + N2 + N3) {
    int j = i - N1 - N2;
    int n = j / (768 * 64);
    int rem = j % (768 * 64);
    int d = rem / 64, k = rem % 64;
    Bo[j] = __float2bfloat16(Wo[((size_t)n * 64 + k) * 768 + d]);
  } else if (i < N1 + N2 + N3 + BB * SS) {
    int j = i - N1 - N2 - N3;
    int b = j / SS, s = j % SS;
    bias2[j] = (1.0f - (float)mask[b * TT + (s & (TT - 1))]) * (-14426.950408889634f);
  }
}

// ---------------------------------------------------------------------------
// Q GEMM: Q[row][64] bf16 = x[row][768] @ Wq[n].  BM=128, BN=64, BK=64.
// A staged f32->bf16 into XOR-swizzled LDS (coalesced 256B/row chunks);
// B frags direct from global (L2-resident).
// ---------------------------------------------------------------------------
__global__ __launch_bounds__(256) void q_gemm_kernel(
    const float* __restrict__ x, const __hip_bfloat16* __restrict__ Bq,
    __hip_bfloat16* __restrict__ Qo)
{
  __shared__ uint As[128 * 32];      // [row][32 u32] = 64 bf16 per row
  const int tid = threadIdx.x;
  const int lane = tid & 63, w = tid >> 6;
  const int wr = w >> 1, wc = w & 1;
  const int cl = lane & 31, hi = lane >> 5;
  const int brow = blockIdx.x * 128;
  const int n = brow >> 12;                     // / (B*T) = 4096
  const float* Asrc = x + (size_t)brow * 768;
  const __hip_bfloat16* Bn = Bq + (size_t)n * 64 * 768;

  f32x16 acc0 = {}, acc1 = {};
  const int r0 = tid >> 3, oct = tid & 7;

  for (int kk = 0; kk < 12; ++kk) {
    __syncthreads();
#pragma unroll
    for (int g = 0; g < 4; ++g) {
      const float* ap = Asrc + (size_t)(r0 + 32 * g) * 768 + kk * 64 + oct * 8;
      float4 f0 = *(const float4*)ap;
      float4 f1 = *(const float4*)(ap + 4);
      int row = r0 + 32 * g;
      u32x4 pk = {pkbf(f0.x, f0.y), pkbf(f0.z, f0.w), pkbf(f1.x, f1.y), pkbf(f1.z, f1.w)};
      *(u32x4*)&As[row * 32 + ((oct ^ (row & 7)) << 2)] = pk;
    }
    __syncthreads();
#pragma unroll
    for (int ks = 0; ks < 4; ++ks) {
      int kg = kk * 64 + ks * 16 + hi * 8;
      u32x4 b = *(const u32x4*)(Bn + (size_t)(wc * 32 + cl) * 768 + kg);
      int ro0 = wr * 64 + cl;
      int ro1 = ro0 + 32;
      int oc = ks * 2 + hi;
      u32x4 a0 = *(const u32x4*)&As[ro0 * 32 + ((oc ^ (ro0 & 7)) << 2)];
      u32x4 a1 = *(const u32x4*)&As[ro1 * 32 + ((oc ^ (ro1 & 7)) << 2)];
      acc0 = mfma32(a0, b, acc0);
      acc1 = mfma32(a1, b, acc1);
    }
  }
  int c = wc * 32 + cl;
#pragma unroll
  for (int r = 0; r < 16; ++r) {
    int rl = (r & 3) + 8 * (r >> 2) + 4 * hi;
    Qo[(size_t)(brow + wr * 64 + rl) * 64 + c] = __float2bfloat16(acc0[r]);
    Qo[(size_t)(brow + wr * 64 + 32 + rl) * 64 + c] = __float2bfloat16(acc1[r]);
  }
}

// ---------------------------------------------------------------------------
// KV GEMM: rows = concat history, BM=128, BN=128 (cols 0-63 K, 64-127 V).
// K row-major [s][64]; V transposed Vt[nb][c][3072].
// ---------------------------------------------------------------------------
__global__ __launch_bounds__(256) void kv_gemm_kernel(
    const float* __restrict__ hist, const __hip_bfloat16* __restrict__ Bkv,
    __hip_bfloat16* __restrict__ Kb, __hip_bfloat16* __restrict__ Vtb)
{
  __shared__ uint As[128 * 32];
  const int tid = threadIdx.x;
  const int lane = tid & 63, w = tid >> 6;
  const int wr = w >> 1, wc = w & 1;
  const int cl = lane & 31, hi = lane >> 5;
  const int brow = blockIdx.x * 128;
  const int nb = brow / SS;
  const int n = nb >> 2, b = nb & 3;
  const int s0 = brow % SS;
  const int p = s0 / TT, t0 = s0 % TT;
  const float* Asrc = hist + (((size_t)(p * NDOM + n) * BB + b) * TT + t0) * 768;

  f32x16 acc00 = {}, acc01 = {}, acc10 = {}, acc11 = {};
  const int r0 = tid >> 3, oct = tid & 7;

  for (int kk = 0; kk < 12; ++kk) {
    __syncthreads();
#pragma unroll
    for (int g = 0; g < 4; ++g) {
      const float* ap = Asrc + (size_t)(r0 + 32 * g) * 768 + kk * 64 + oct * 8;
      float4 f0 = *(const float4*)ap;
      float4 f1 = *(const float4*)(ap + 4);
      int row = r0 + 32 * g;
      u32x4 pk = {pkbf(f0.x, f0.y), pkbf(f0.z, f0.w), pkbf(f1.x, f1.y), pkbf(f1.z, f1.w)};
      *(u32x4*)&As[row * 32 + ((oct ^ (row & 7)) << 2)] = pk;
    }
    __syncthreads();
#pragma unroll
    for (int ks = 0; ks < 4; ++ks) {
      int kg = kk * 64 + ks * 16 + hi * 8;
      u32x4 b0 = *(const u32x4*)(Bkv + (size_t)(wc * 64 + cl) * 768 + kg);
      u32x4 b1 = *(const u32x4*)(Bkv + (size_t)(wc * 64 + 32 + cl) * 768 + kg);
      int ro0 = wr * 64 + cl;
      int ro1 = ro0 + 32;
      int oc = ks * 2 + hi;
      u32x4 a0 = *(const u32x4*)&As[ro0 * 32 + ((oc ^ (ro0 & 7)) << 2)];
      u32x4 a1 = *(const u32x4*)&As[ro1 * 32 + ((oc ^ (ro1 & 7)) << 2)];
      acc00 = mfma32(a0, b0, acc00);
      acc01 = mfma32(a0, b1, acc01);
      acc10 = mfma32(a1, b0, acc10);
      acc11 = mfma32(a1, b1, acc11);
    }
  }

  if (wc == 0) {   // K half
#pragma unroll
    for (int r = 0; r < 16; ++r) {
      int rl = (r & 3) + 8 * (r >> 2) + 4 * hi;
      size_t rbase0 = (size_t)(brow + wr * 64 + rl) * 64;
      size_t rbase1 = (size_t)(brow + wr * 64 + 32 + rl) * 64;
      Kb[rbase0 + cl]      = __float2bfloat16(acc00[r]);
      Kb[rbase0 + 32 + cl] = __float2bfloat16(acc01[r]);
      Kb[rbase1 + cl]      = __float2bfloat16(acc10[r]);
      Kb[rbase1 + 32 + cl] = __float2bfloat16(acc11[r]);
    }
  } else {         // V half -> Vt
#pragma unroll
    for (int k = 0; k < 4; ++k) {
      int sl0 = s0 + wr * 64 + 8 * k + 4 * hi;
      __hip_bfloat16* v0 = Vtb + ((size_t)nb * 64 + cl) * SS + sl0;
      __hip_bfloat16* v1 = Vtb + ((size_t)nb * 64 + 32 + cl) * SS + sl0;
      *(uint2*)v0        = uint2{pkbf(acc00[4*k], acc00[4*k+1]), pkbf(acc00[4*k+2], acc00[4*k+3])};
      *(uint2*)v1        = uint2{pkbf(acc01[4*k], acc01[4*k+1]), pkbf(acc01[4*k+2], acc01[4*k+3])};
      *(uint2*)(v0 + 32) = uint2{pkbf(acc10[4*k], acc10[4*k+1]), pkbf(acc10[4*k+2], acc10[4*k+3])};
      *(uint2*)(v1 + 32) = uint2{pkbf(acc11[4*k], acc11[4*k+1]), pkbf(acc11[4*k+2], acc11[4*k+3])};
    }
  }
}

// ---------------------------------------------------------------------------
// Flash attention, split-S by 4.  1 wave = 32 queries, 768 keys, 64 keys/iter.
// Swapped QK^T; O^T accum; exp2-domain online softmax (f32x2-packed) with
// defer-max; permlane32_swap P repack.  bf16 partials + (m,l) to workspace.
// ---------------------------------------------------------------------------
struct KV { u32x4 k0, k1, k2, k3, v0, v1, v2, v3; };

__global__ __launch_bounds__(64) void attn_kernel(
    const __hip_bfloat16* __restrict__ Q, const __hip_bfloat16* __restrict__ K,
    const __hip_bfloat16* __restrict__ Vt, const float* __restrict__ bias2,
    __hip_bfloat16* __restrict__ Op, float* __restrict__ Mp, float* __restrict__ Lp)
{
  const int lane = threadIdx.x;
  const int cl = lane & 31, hi = lane >> 5;
  const int bid = blockIdx.x;
  const int g = bid % 48;            // (n,b,h) group -> fixed XCD (48 % 8 == 0)
  const int rest = bid / 48;         // 0..127
  const int sp = rest >> 5;          // split 0..3
  const int tile = rest & 31;        // q tile 0..31
  const int h = g & 1, nb = g >> 1;
  const int b = nb & 3;
  const int qrow = nb * TT + tile * 32;
  const int sbase = sp * (SS / NSPLIT);   // 768 keys per split

  const __hip_bfloat16* Qp = Q + (size_t)(qrow + cl) * 64 + h * 32 + hi * 8;
  u32x4 qf0 = *(const u32x4*)Qp;
  u32x4 qf1 = *(const u32x4*)(Qp + 16);

  const __hip_bfloat16* Kp = K + ((size_t)nb * SS + sbase + cl) * 64 + h * 32 + hi * 8;
  const __hip_bfloat16* Vp = Vt + ((size_t)nb * 64 + h * 32 + cl) * SS + sbase + hi * 8;
  const float* Bp = bias2 + b * SS + sbase + hi * 4;

  const float scale2 = 0.17677669529663687f * 1.4426950408889634f;
  const f32x2 sc2 = {scale2, scale2};

  f32x16 ot = {};
  float m = -1e30f, lsum = 0.f;

  auto loadKV = [&](int it) {
    KV t;
    const __hip_bfloat16* kp = Kp + (size_t)it * 64 * 64;
    t.k0 = *(const u32x4*)kp;
    t.k1 = *(const u32x4*)(kp + 16);
    t.k2 = *(const u32x4*)(kp + 32 * 64);
    t.k3 = *(const u32x4*)(kp + 32 * 64 + 16);
    const __hip_bfloat16* vp = Vp + it * 64;
    t.v0 = *(const u32x4*)vp;
    t.v1 = *(const u32x4*)(vp + 16);
    t.v2 = *(const u32x4*)(vp + 32);
    t.v3 = *(const u32x4*)(vp + 48);
    return t;
  };

  auto compute = [&](const KV& t, int it) {
    f32x16 pz0 = {}, pz1 = {};
    pz0 = mfma32(t.k0, qf0, pz0);
    pz0 = mfma32(t.k1, qf1, pz0);
    pz1 = mfma32(t.k2, qf0, pz1);
    pz1 = mfma32(t.k3, qf1, pz1);
    const float* bp = Bp + it * 64;
    f32x4 b4[8];
#pragma unroll
    for (int q = 0; q < 8; ++q) b4[q] = *(const f32x4*)(bp + 8 * q);
    f32x2 p2[16];
#pragma unroll
    for (int i = 0; i < 8; ++i) {
      f32x4 bq0 = b4[i >> 1];
      f32x4 bq1 = b4[4 + (i >> 1)];
      f32x2 bv0 = (i & 1) ? f32x2{bq0.z, bq0.w} : f32x2{bq0.x, bq0.y};
      f32x2 bv1 = (i & 1) ? f32x2{bq1.z, bq1.w} : f32x2{bq1.x, bq1.y};
      p2[i]     = f32x2{pz0[2*i], pz0[2*i+1]} * sc2 + bv0;
      p2[8 + i] = f32x2{pz1[2*i], pz1[2*i+1]} * sc2 + bv1;
    }
    f32x2 mx = p2[0];
#pragma unroll
    for (int i = 1; i < 16; ++i) {
      mx.x = fmaxf(mx.x, p2[i].x);
      mx.y = fmaxf(mx.y, p2[i].y);
    }
    float tm = fmaxf(mx.x, mx.y);
    tm = fmaxf(tm, __shfl_xor(tm, 32));
    if (!__all(tm - m <= 8.f)) {       // defer-max
      float mn = fmaxf(m, tm);
      float f = exp2f(m - mn);
#pragma unroll
      for (int i = 0; i < 16; ++i) ot[i] *= f;
      lsum *= f;
      m = mn;
    }
    const f32x2 m2 = {m, m};
    f32x2 s2 = {0.f, 0.f};
#pragma unroll
    for (int i = 0; i < 16; ++i) {
      f32x2 d = p2[i] - m2;
      f32x2 e = {exp2f(d.x), exp2f(d.y)};
      p2[i] = e;
      s2 += e;
    }
    float ts = s2.x + s2.y;
    ts += __shfl_xor(ts, 32);
    lsum += ts;
    // P -> bf16 B-frags via permlane32_swap
    uint cv[16];
#pragma unroll
    for (int i = 0; i < 16; ++i) cv[i] = pkbf(p2[i].x, p2[i].y);
    u32x4 pf0, pf1, pf2, pf3;
    {
      uint x0, y0, x1, y1;
      plswap(cv[0], cv[2],  x0, y0); plswap(cv[1], cv[3],  x1, y1);
      pf0 = u32x4{x0, x1, y0, y1};
      plswap(cv[4], cv[6],  x0, y0); plswap(cv[5], cv[7],  x1, y1);
      pf1 = u32x4{x0, x1, y0, y1};
      plswap(cv[8], cv[10], x0, y0); plswap(cv[9], cv[11], x1, y1);
      pf2 = u32x4{x0, x1, y0, y1};
      plswap(cv[12], cv[14], x0, y0); plswap(cv[13], cv[15], x1, y1);
      pf3 = u32x4{x0, x1, y0, y1};
    }
    ot = mfma32(t.v0, pf0, ot);
    ot = mfma32(t.v1, pf1, ot);
    ot = mfma32(t.v2, pf2, ot);
    ot = mfma32(t.v3, pf3, ot);
  };

  KV cur = loadKV(0);
#pragma unroll 1
  for (int it = 0; it < 12; ++it) {
    KV nxt = loadKV(it + 1 < 12 ? it + 1 : 11);
    compute(cur, it);
    cur = nxt;
  }

  // store unnormalized O^T partial (bf16) + m/l
  __hip_bfloat16* op = Op + ((size_t)sp * NROW + qrow + cl) * 64 + h * 32 + 4 * hi;
#pragma unroll
  for (int k = 0; k < 4; ++k) {
    uint2 wv = {pkbf(ot[4*k], ot[4*k+1]), pkbf(ot[4*k+2], ot[4*k+3])};
    *(uint2*)(op + 8 * k) = wv;
  }
  if (lane < 32) {
    int mi = ((sp * 24 + nb) * 2 + h) * TT + tile * 32 + cl;
    Mp[mi] = m;
    Lp[mi] = lsum;
  }
}

// ---------------------------------------------------------------------------
// Fused split-combine + out-projection (MFMA) + residual + LayerNorm.
// Block 256 = 4 waves, 32 rows; wave w owns cols [w*192, +192).
// ---------------------------------------------------------------------------
__global__ __launch_bounds__(256) void oproj_ln_kernel(
    const float* __restrict__ x, const __hip_bfloat16* __restrict__ Op,
    const float* __restrict__ Mp, const float* __restrict__ Lp,
    const __hip_bfloat16* __restrict__ Bo, const float* __restrict__ gamma,
    const float* __restrict__ beta, float* __restrict__ out)
{
  __shared__ float red[4][32][2];
  __shared__ float redf[32][2];
  const int tid = threadIdx.x;
  const int lane = tid & 63, w = tid >> 6;
  const int cl = lane & 31, hi = lane >> 5;
  const int row0 = blockIdx.x * 32;
  const int n = row0 >> 12;
  const int nb = row0 >> 10;
  const int trow = (row0 & 1023) + cl;
  const int MLS = 24 * 2 * TT;

  // combine weights per head
  float wsp[2][NSPLIT];
#pragma unroll
  for (int h = 0; h < 2; ++h) {
    int mi = (nb * 2 + h) * TT + trow;
    float mv[NSPLIT], lv[NSPLIT];
#pragma unroll
    for (int sp = 0; sp < NSPLIT; ++sp) { mv[sp] = Mp[mi + sp * MLS]; lv[sp] = Lp[mi + sp * MLS]; }
    float ms = mv[0];
#pragma unroll
    for (int sp = 1; sp < NSPLIT; ++sp) ms = fmaxf(ms, mv[sp]);
    float den = 0.f;
#pragma unroll
    for (int sp = 0; sp < NSPLIT; ++sp) { wsp[h][sp] = exp2f(mv[sp] - ms); den = fmaf(lv[sp], wsp[h][sp], den); }
    float inv = 1.0f / den;
#pragma unroll
    for (int sp = 0; sp < NSPLIT; ++sp) wsp[h][sp] *= inv;
  }

  // A-frags: combine partials
  u32x4 af[4];
#pragma unroll
  for (int ks = 0; ks < 4; ++ks) {
    int h = ks >> 1;
    size_t off = (size_t)(row0 + cl) * 64 + ks * 16 + hi * 8;
    f32x2 s0 = {}, s1 = {}, s2 = {}, s3 = {};
#pragma unroll
    for (int sp = 0; sp < NSPLIT; ++sp) {
      u32x4 v = *(const u32x4*)(Op + (size_t)sp * NROW * 64 + off);
      float wv = wsp[h][sp];
      s0 += f32x2{b2f(v[0] & 0xffffu), b2f(v[0] >> 16)} * wv;
      s1 += f32x2{b2f(v[1] & 0xffffu), b2f(v[1] >> 16)} * wv;
      s2 += f32x2{b2f(v[2] & 0xffffu), b2f(v[2] >> 16)} * wv;
      s3 += f32x2{b2f(v[3] & 0xffffu), b2f(v[3] >> 16)} * wv;
    }
    af[ks] = u32x4{pkbf(s0.x, s0.y), pkbf(s1.x, s1.y), pkbf(s2.x, s2.y), pkbf(s3.x, s3.y)};
  }

  const __hip_bfloat16* Bp = Bo + ((size_t)n * 768 + w * 192 + cl) * 64 + hi * 8;
  f32x16 acc[6] = {};
#pragma unroll
  for (int ks = 0; ks < 4; ++ks) {
#pragma unroll
    for (int t = 0; t < 6; ++t) {
      u32x4 bb = *(const u32x4*)(Bp + (size_t)(t * 32) * 64 + ks * 16);
      acc[t] = mfma32(af[ks], bb, acc[t]);
    }
  }

  float s1[16], s2[16];
#pragma unroll
  for (int r = 0; r < 16; ++r) { s1[r] = 0.f; s2[r] = 0.f; }
#pragma unroll
  for (int t = 0; t < 6; ++t) {
#pragma unroll
    for (int r = 0; r < 16; ++r) {
      int R = (r & 3) + 8 * (r >> 2) + 4 * hi;
      int col = w * 192 + t * 32 + cl;
      float y = acc[t][r] + x[(size_t)(row0 + R) * 768 + col];
      acc[t][r] = y;
      s1[r] += y;
      s2[r] = fmaf(y, y, s2[r]);
    }
  }
#pragma unroll
  for (int r = 0; r < 16; ++r) {
#pragma unroll
    for (int off = 1; off < 32; off <<= 1) {
      s1[r] += __shfl_xor(s1[r], off);
      s2[r] += __shfl_xor(s2[r], off);
    }
  }
  if (cl == 0) {
#pragma unroll
    for (int r = 0; r < 16; ++r) {
      int R = (r & 3) + 8 * (r >> 2) + 4 * hi;
      red[w][R][0] = s1[r];
      red[w][R][1] = s2[r];
    }
  }
  __syncthreads();
  if (tid < 64) {
    int R = tid & 31, st = tid >> 5;
    redf[R][st] = red[0][R][st] + red[1][R][st] + red[2][R][st] + red[3][R][st];
  }
  __syncthreads();

  float gv[6], bv[6];
#pragma unroll
  for (int t = 0; t < 6; ++t) {
    int col = w * 192 + t * 32 + cl;
    gv[t] = gamma[n * 768 + col];
    bv[t] = beta[n * 768 + col];
  }
#pragma unroll
  for (int r = 0; r < 16; ++r) {
    int R = (r & 3) + 8 * (r >> 2) + 4 * hi;
    float mu = redf[R][0] * (1.0f / 768.0f);
    float var = redf[R][1] * (1.0f / 768.0f) - mu * mu;
    float rs = rsqrtf(var + LNEPS);
#pragma unroll
    for (int t = 0; t < 6; ++t) {
      int col = w * 192 + t * 32 + cl;
      out[(size_t)(row0 + R) * 768 + col] = (acc[t][r] - mu) * rs * gv[t] + bv[t];
    }
  }
}

// ---------------------------------------------------------------------------
extern "C" void kernel_launch(void* const* d_in, const int* in_sizes, int n_in,
                              void* d_out, int out_size, void* d_ws, size_t ws_size,
                              hipStream_t stream) {
  const float* x     = (const float*)d_in[0];
  const float* hist  = (const float*)d_in[1];
  const int*   mask  = (const int*)d_in[2];
  const float* Wq    = (const float*)d_in[3];
  const float* Wk    = (const float*)d_in[4];
  const float* Wv    = (const float*)d_in[5];
  const float* Wo    = (const float*)d_in[6];
  const float* gamma = (const float*)d_in[7];
  const float* beta  = (const float*)d_in[8];
  float* out = (float*)d_out;

  char* ws = (char*)d_ws;
  __hip_bfloat16* Qb  = (__hip_bfloat16*)ws;  ws += (size_t)NROW * II * 2;
  __hip_bfloat16* Kb  = (__hip_bfloat16*)ws;  ws += (size_t)NKVROW * II * 2;
  __hip_bfloat16* Vtb = (__hip_bfloat16*)ws;  ws += (size_t)NDOM*BB*II * SS * 2;
  __hip_bfloat16* Op  = (__hip_bfloat16*)ws;  ws += (size_t)NSPLIT * NROW * II * 2;
  float* Mp           = (float*)ws;           ws += (size_t)NSPLIT * 24 * 2 * TT * 4;
  float* Lp           = (float*)ws;           ws += (size_t)NSPLIT * 24 * 2 * TT * 4;
  __hip_bfloat16* Bkv = (__hip_bfloat16*)ws;  ws += (size_t)128 * 768 * 2;
  __hip_bfloat16* Bq  = (__hip_bfloat16*)ws;  ws += (size_t)NDOM * 64 * 768 * 2;
  __hip_bfloat16* Bo  = (__hip_bfloat16*)ws;  ws += (size_t)NDOM * 768 * 64 * 2;
  float* bias2        = (float*)ws;           ws += (size_t)BB * SS * 4;

  const int PREP_N = 128*768 + NDOM*64*768 + NDOM*768*64 + BB*SS;
  prep_kernel<<<(PREP_N + 255) / 256, 256, 0, stream>>>(mask, Wk, Wv, Wq, Wo, Bkv, Bq, Bo, bias2);
  q_gemm_kernel<<<NROW / 128, 256, 0, stream>>>(x, Bq, Qb);
  kv_gemm_kernel<<<NKVROW / 128, 256, 0, stream>>>(hist, Bkv, Kb, Vtb);
  attn_kernel<<<48 * 32 * NSPLIT, 64, 0, stream>>>(Qb, Kb, Vtb, bias2, Op, Mp, Lp);
  oproj_ln_kernel<<<NROW / 32, 256, 0, stream>>>(x, Op, Mp, Lp, Bo, gamma, beta, out);
}

// Round 7
// 234.709 us; speedup vs baseline: 1.3282x; 1.0815x over previous
//
#include <hip/hip_runtime.h>
#include <hip/hip_bf16.h>
#include <math.h>

#define NDOM 6
#define BB 4
#define TT 1024
#define DD 768
#define PP 3
#define HH 2
#define DHH 32
#define II 64
#define SS (PP*TT)        // 3072
#define NROW (NDOM*BB*TT) // 24576
#define NKVROW (NDOM*BB*SS)
#define NSPLIT 4
#define LNEPS 1e-5f

typedef unsigned int uint;
typedef uint  u32x4  __attribute__((ext_vector_type(4)));
typedef int   i32x2  __attribute__((ext_vector_type(2)));
typedef float f32x2  __attribute__((ext_vector_type(2)));
typedef float f32x4  __attribute__((ext_vector_type(4)));
typedef float f32x16 __attribute__((ext_vector_type(16)));
typedef __bf16 bf16x8 __attribute__((ext_vector_type(8)));

// D = A(32x16) * B(16x32) + C.  A row = lane&31, k = (lane>>5)*8+j.
// B col = lane&31, k = (lane>>5)*8+j.  D: col = lane&31, row=(r&3)+8*(r>>2)+4*(lane>>5).
__device__ __forceinline__ f32x16 mfma32(u32x4 a, u32x4 b, f32x16 c) {
  return __builtin_amdgcn_mfma_f32_32x32x16_bf16(
      __builtin_bit_cast(bf16x8, a), __builtin_bit_cast(bf16x8, b), c, 0, 0, 0);
}

__device__ __forceinline__ uint pkbf(float a, float b) {
  union { __bf16 h[2]; uint u; } v;
  v.h[0] = (__bf16)a; v.h[1] = (__bf16)b;
  return v.u;
}
__device__ __forceinline__ float b2f(uint u16) {
  union { uint i; float f; } v; v.i = u16 << 16; return v.f;
}

// x gets {a_lo | partner's b}, y gets {partner's a | b}  (32-lane halves)
__device__ __forceinline__ void plswap(uint a, uint b, uint& x, uint& y) {
#if __has_builtin(__builtin_amdgcn_permlane32_swap)
  i32x2 r = __builtin_amdgcn_permlane32_swap((int)a, (int)b, false, false);
  x = (uint)r.x; y = (uint)r.y;
#else
  uint sa = __shfl_xor(a, 32), sb = __shfl_xor(b, 32);
  bool h1 = (threadIdx.x & 32) != 0;
  x = h1 ? sb : a;
  y = h1 ? b : sa;
#endif
}

// ---------------------------------------------------------------------------
// Prep: bf16 transposed weights + exp2-domain mask bias.
// ---------------------------------------------------------------------------
__global__ __launch_bounds__(256) void prep_kernel(
    const int* __restrict__ mask, const float* __restrict__ Wk,
    const float* __restrict__ Wv, const float* __restrict__ Wq,
    const float* __restrict__ Wo,
    __hip_bfloat16* __restrict__ Bkv, __hip_bfloat16* __restrict__ Bq,
    __hip_bfloat16* __restrict__ Bo, float* __restrict__ bias2)
{
  int i = blockIdx.x * 256 + threadIdx.x;
  const int N1 = 128 * 768;          // Bkv
  const int N2 = NDOM * 64 * 768;    // Bq
  const int N3 = NDOM * 768 * 64;    // Bo
  if (i < N1) {
    int c = i / 768, k = i % 768;
    float v = (c < 64) ? Wk[k * 64 + c] : Wv[k * 64 + (c - 64)];
    Bkv[i] = __float2bfloat16(v);
  } else if (i < N1 + N2) {
    int j = i - N1;
    int n = j / (64 * 768);
    int rem = j % (64 * 768);
    int c = rem / 768, k = rem % 768;
    Bq[j] = __float2bfloat16(Wq[((size_t)n * 768 + k) * 64 + c]);
  } else if (i < N1 + N2 + N3) {
    int j = i - N1 - N2;
    int n = j / (768 * 64);
    int rem = j % (768 * 64);
    int d = rem / 64, k = rem % 64;
    Bo[j] = __float2bfloat16(Wo[((size_t)n * 64 + k) * 768 + d]);
  } else if (i < N1 + N2 + N3 + BB * SS) {
    int j = i - N1 - N2 - N3;
    int b = j / SS, s = j % SS;
    bias2[j] = (1.0f - (float)mask[b * TT + (s & (TT - 1))]) * (-14426.950408889634f);
  }
}

// ---------------------------------------------------------------------------
// Q GEMM: Q[row][64] bf16 = x[row][768] @ Wq[n].  BM=128, BN=64, BK=64.
// A staged f32->bf16 into XOR-swizzled LDS; B frags direct from global.
// ---------------------------------------------------------------------------
__global__ __launch_bounds__(256) void q_gemm_kernel(
    const float* __restrict__ x, const __hip_bfloat16* __restrict__ Bq,
    __hip_bfloat16* __restrict__ Qo)
{
  __shared__ uint As[128 * 32];      // [row][32 u32] = 64 bf16 per row
  const int tid = threadIdx.x;
  const int lane = tid & 63, w = tid >> 6;
  const int wr = w >> 1, wc = w & 1;
  const int cl = lane & 31, hi = lane >> 5;
  const int brow = blockIdx.x * 128;
  const int n = brow >> 12;                     // / (B*T) = 4096
  const float* Asrc = x + (size_t)brow * 768;
  const __hip_bfloat16* Bn = Bq + (size_t)n * 64 * 768;

  f32x16 acc0 = {}, acc1 = {};
  const int r0 = tid >> 3, oct = tid & 7;

  for (int kk = 0; kk < 12; ++kk) {
    __syncthreads();
#pragma unroll
    for (int g = 0; g < 4; ++g) {
      const float* ap = Asrc + (size_t)(r0 + 32 * g) * 768 + kk * 64 + oct * 8;
      float4 f0 = *(const float4*)ap;
      float4 f1 = *(const float4*)(ap + 4);
      int row = r0 + 32 * g;
      u32x4 pk = {pkbf(f0.x, f0.y), pkbf(f0.z, f0.w), pkbf(f1.x, f1.y), pkbf(f1.z, f1.w)};
      *(u32x4*)&As[row * 32 + ((oct ^ (row & 7)) << 2)] = pk;
    }
    __syncthreads();
#pragma unroll
    for (int ks = 0; ks < 4; ++ks) {
      int kg = kk * 64 + ks * 16 + hi * 8;
      u32x4 b = *(const u32x4*)(Bn + (size_t)(wc * 32 + cl) * 768 + kg);
      int ro0 = wr * 64 + cl;
      int ro1 = ro0 + 32;
      int oc = ks * 2 + hi;
      u32x4 a0 = *(const u32x4*)&As[ro0 * 32 + ((oc ^ (ro0 & 7)) << 2)];
      u32x4 a1 = *(const u32x4*)&As[ro1 * 32 + ((oc ^ (ro1 & 7)) << 2)];
      acc0 = mfma32(a0, b, acc0);
      acc1 = mfma32(a1, b, acc1);
    }
  }
  int c = wc * 32 + cl;
#pragma unroll
  for (int r = 0; r < 16; ++r) {
    int rl = (r & 3) + 8 * (r >> 2) + 4 * hi;
    Qo[(size_t)(brow + wr * 64 + rl) * 64 + c] = __float2bfloat16(acc0[r]);
    Qo[(size_t)(brow + wr * 64 + 32 + rl) * 64 + c] = __float2bfloat16(acc1[r]);
  }
}

// ---------------------------------------------------------------------------
// KV GEMM: rows = concat history, BM=128, BN=128 (cols 0-63 K, 64-127 V).
// K head-split:  Kh[nb][h][s][32]      (coalesced attn K loads, L2-friendly)
// V sub-blocked: Vt2[nb][h][s/8][c][8] (coalesced attn V loads)
// ---------------------------------------------------------------------------
__global__ __launch_bounds__(256) void kv_gemm_kernel(
    const float* __restrict__ hist, const __hip_bfloat16* __restrict__ Bkv,
    __hip_bfloat16* __restrict__ Kh, __hip_bfloat16* __restrict__ Vt2)
{
  __shared__ uint As[128 * 32];
  const int tid = threadIdx.x;
  const int lane = tid & 63, w = tid >> 6;
  const int wr = w >> 1, wc = w & 1;
  const int cl = lane & 31, hi = lane >> 5;
  const int brow = blockIdx.x * 128;
  const int nb = brow / SS;
  const int n = nb >> 2, b = nb & 3;
  const int s0 = brow % SS;
  const int p = s0 / TT, t0 = s0 % TT;
  const float* Asrc = hist + (((size_t)(p * NDOM + n) * BB + b) * TT + t0) * 768;

  f32x16 acc00 = {}, acc01 = {}, acc10 = {}, acc11 = {};
  const int r0 = tid >> 3, oct = tid & 7;

  for (int kk = 0; kk < 12; ++kk) {
    __syncthreads();
#pragma unroll
    for (int g = 0; g < 4; ++g) {
      const float* ap = Asrc + (size_t)(r0 + 32 * g) * 768 + kk * 64 + oct * 8;
      float4 f0 = *(const float4*)ap;
      float4 f1 = *(const float4*)(ap + 4);
      int row = r0 + 32 * g;
      u32x4 pk = {pkbf(f0.x, f0.y), pkbf(f0.z, f0.w), pkbf(f1.x, f1.y), pkbf(f1.z, f1.w)};
      *(u32x4*)&As[row * 32 + ((oct ^ (row & 7)) << 2)] = pk;
    }
    __syncthreads();
#pragma unroll
    for (int ks = 0; ks < 4; ++ks) {
      int kg = kk * 64 + ks * 16 + hi * 8;
      u32x4 b0 = *(const u32x4*)(Bkv + (size_t)(wc * 64 + cl) * 768 + kg);
      u32x4 b1 = *(const u32x4*)(Bkv + (size_t)(wc * 64 + 32 + cl) * 768 + kg);
      int ro0 = wr * 64 + cl;
      int ro1 = ro0 + 32;
      int oc = ks * 2 + hi;
      u32x4 a0 = *(const u32x4*)&As[ro0 * 32 + ((oc ^ (ro0 & 7)) << 2)];
      u32x4 a1 = *(const u32x4*)&As[ro1 * 32 + ((oc ^ (ro1 & 7)) << 2)];
      acc00 = mfma32(a0, b0, acc00);
      acc01 = mfma32(a0, b1, acc01);
      acc10 = mfma32(a1, b0, acc10);
      acc11 = mfma32(a1, b1, acc11);
    }
  }

  if (wc == 0) {   // K half: cols 0..63 -> heads 0/1, dims cl
    const size_t base0 = ((size_t)(nb * 2 + 0) * SS);
    const size_t base1 = ((size_t)(nb * 2 + 1) * SS);
#pragma unroll
    for (int r = 0; r < 16; ++r) {
      int rl = (r & 3) + 8 * (r >> 2) + 4 * hi;
      int s  = s0 + wr * 64 + rl;
      Kh[(base0 + s) * 32 + cl]      = __float2bfloat16(acc00[r]);
      Kh[(base1 + s) * 32 + cl]      = __float2bfloat16(acc01[r]);
      Kh[(base0 + s + 32) * 32 + cl] = __float2bfloat16(acc10[r]);
      Kh[(base1 + s + 32) * 32 + cl] = __float2bfloat16(acc11[r]);
    }
  } else {         // V half: cols 64..127 -> Vt2[nb][h][sb][c][8]
#pragma unroll
    for (int k = 0; k < 4; ++k) {
      int sb0 = (s0 + wr * 64 + 8 * k) >> 3;         // group of v0/v1 accs 0..3
      int sb1 = sb0 + 4;                              // +32 keys for acc1x
      size_t a00 = (((size_t)(nb * 2 + 0) * (SS / 8) + sb0) * 32 + cl) * 8 + 4 * hi;
      size_t a01 = (((size_t)(nb * 2 + 1) * (SS / 8) + sb0) * 32 + cl) * 8 + 4 * hi;
      size_t a10 = (((size_t)(nb * 2 + 0) * (SS / 8) + sb1) * 32 + cl) * 8 + 4 * hi;
      size_t a11 = (((size_t)(nb * 2 + 1) * (SS / 8) + sb1) * 32 + cl) * 8 + 4 * hi;
      *(uint2*)(Vt2 + a00) = uint2{pkbf(acc00[4*k], acc00[4*k+1]), pkbf(acc00[4*k+2], acc00[4*k+3])};
      *(uint2*)(Vt2 + a01) = uint2{pkbf(acc01[4*k], acc01[4*k+1]), pkbf(acc01[4*k+2], acc01[4*k+3])};
      *(uint2*)(Vt2 + a10) = uint2{pkbf(acc10[4*k], acc10[4*k+1]), pkbf(acc10[4*k+2], acc10[4*k+3])};
      *(uint2*)(Vt2 + a11) = uint2{pkbf(acc11[4*k], acc11[4*k+1]), pkbf(acc11[4*k+2], acc11[4*k+3])};
    }
  }
}

// ---------------------------------------------------------------------------
// Flash attention, split-S by 4.  Block = 4 waves sharing one (n,b,h,split):
// wave w owns q-tile tq*4+w (32 queries); all waves stream the SAME K/V tiles
// in lockstep (raw s_barrier per iter, no LDS) -> L1 broadcast hits.
// Coalesced K (head-split rows of 64B) and V (8-key sub-blocks).
// ---------------------------------------------------------------------------
struct KV { u32x4 k0, k1, k2, k3, v0, v1, v2, v3; };

__global__ __launch_bounds__(256) void attn_kernel(
    const __hip_bfloat16* __restrict__ Q, const __hip_bfloat16* __restrict__ Kh,
    const __hip_bfloat16* __restrict__ Vt2, const float* __restrict__ bias2,
    __hip_bfloat16* __restrict__ Op, float* __restrict__ Mp, float* __restrict__ Lp)
{
  const int tid = threadIdx.x;
  const int lane = tid & 63, w = tid >> 6;
  const int cl = lane & 31, hi = lane >> 5;
  const int bid = blockIdx.x;
  const int g = bid % 48;            // (n,b,h) group -> fixed XCD (48 % 8 == 0)
  const int rest = bid / 48;         // 0..31
  const int sp = rest >> 3;          // split 0..3
  const int tq = rest & 7;           // q super-tile 0..7
  const int qtile = tq * 4 + w;      // 0..31
  const int h = g & 1, nb = g >> 1;
  const int b = nb & 3;
  const int qrow = nb * TT + qtile * 32;
  const int sbase = sp * (SS / NSPLIT);   // 768 keys per split

  const __hip_bfloat16* Qp = Q + (size_t)(qrow + cl) * 64 + h * 32 + hi * 8;
  u32x4 qf0 = *(const u32x4*)Qp;
  u32x4 qf1 = *(const u32x4*)(Qp + 16);

  const __hip_bfloat16* Kp = Kh + ((size_t)(nb * 2 + h) * SS + sbase) * 32;
  const __hip_bfloat16* Vp = Vt2 + (size_t)(nb * 2 + h) * SS * 32 + (size_t)sbase * 32;
  const float* Bp = bias2 + b * SS + sbase + hi * 4;

  const float scale2 = 0.17677669529663687f * 1.4426950408889634f;
  const f32x2 sc2 = {scale2, scale2};

  f32x16 ot = {};
  float m = -1e30f, lsum = 0.f;

  auto loadKV = [&](int it) {
    KV t;
    const __hip_bfloat16* kp = Kp + (size_t)it * 64 * 32;
    t.k0 = *(const u32x4*)(kp + cl * 32 + hi * 8);
    t.k1 = *(const u32x4*)(kp + cl * 32 + 16 + hi * 8);
    t.k2 = *(const u32x4*)(kp + 1024 + cl * 32 + hi * 8);
    t.k3 = *(const u32x4*)(kp + 1024 + cl * 32 + 16 + hi * 8);
    const __hip_bfloat16* vp = Vp + (size_t)it * 64 * 32;
    t.v0 = *(const u32x4*)(vp + ((0 * 2 + hi) * 32 + cl) * 8);
    t.v1 = *(const u32x4*)(vp + ((1 * 2 + hi) * 32 + cl) * 8);
    t.v2 = *(const u32x4*)(vp + ((2 * 2 + hi) * 32 + cl) * 8);
    t.v3 = *(const u32x4*)(vp + ((3 * 2 + hi) * 32 + cl) * 8);
    return t;
  };

  auto compute = [&](const KV& t, int it) {
    f32x16 pz0 = {}, pz1 = {};
    pz0 = mfma32(t.k0, qf0, pz0);
    pz0 = mfma32(t.k1, qf1, pz0);
    pz1 = mfma32(t.k2, qf0, pz1);
    pz1 = mfma32(t.k3, qf1, pz1);
    const float* bp = Bp + it * 64;
    f32x4 b4[8];
#pragma unroll
    for (int q = 0; q < 8; ++q) b4[q] = *(const f32x4*)(bp + 8 * q);
    f32x2 p2[16];
#pragma unroll
    for (int i = 0; i < 8; ++i) {
      f32x4 bq0 = b4[i >> 1];
      f32x4 bq1 = b4[4 + (i >> 1)];
      f32x2 bv0 = (i & 1) ? f32x2{bq0.z, bq0.w} : f32x2{bq0.x, bq0.y};
      f32x2 bv1 = (i & 1) ? f32x2{bq1.z, bq1.w} : f32x2{bq1.x, bq1.y};
      p2[i]     = f32x2{pz0[2*i], pz0[2*i+1]} * sc2 + bv0;
      p2[8 + i] = f32x2{pz1[2*i], pz1[2*i+1]} * sc2 + bv1;
    }
    f32x2 mx = p2[0];
#pragma unroll
    for (int i = 1; i < 16; ++i) {
      mx.x = fmaxf(mx.x, p2[i].x);
      mx.y = fmaxf(mx.y, p2[i].y);
    }
    float tm = fmaxf(mx.x, mx.y);
    tm = fmaxf(tm, __shfl_xor(tm, 32));
    if (!__all(tm - m <= 8.f)) {       // defer-max
      float mn = fmaxf(m, tm);
      float f = exp2f(m - mn);
#pragma unroll
      for (int i = 0; i < 16; ++i) ot[i] *= f;
      lsum *= f;
      m = mn;
    }
    const f32x2 m2 = {m, m};
    f32x2 s2 = {0.f, 0.f};
#pragma unroll
    for (int i = 0; i < 16; ++i) {
      f32x2 d = p2[i] - m2;
      f32x2 e = {exp2f(d.x), exp2f(d.y)};
      p2[i] = e;
      s2 += e;
    }
    float ts = s2.x + s2.y;
    ts += __shfl_xor(ts, 32);
    lsum += ts;
    // P -> bf16 B-frags via permlane32_swap
    uint cv[16];
#pragma unroll
    for (int i = 0; i < 16; ++i) cv[i] = pkbf(p2[i].x, p2[i].y);
    u32x4 pf0, pf1, pf2, pf3;
    {
      uint x0, y0, x1, y1;
      plswap(cv[0], cv[2],  x0, y0); plswap(cv[1], cv[3],  x1, y1);
      pf0 = u32x4{x0, x1, y0, y1};
      plswap(cv[4], cv[6],  x0, y0); plswap(cv[5], cv[7],  x1, y1);
      pf1 = u32x4{x0, x1, y0, y1};
      plswap(cv[8], cv[10], x0, y0); plswap(cv[9], cv[11], x1, y1);
      pf2 = u32x4{x0, x1, y0, y1};
      plswap(cv[12], cv[14], x0, y0); plswap(cv[13], cv[15], x1, y1);
      pf3 = u32x4{x0, x1, y0, y1};
    }
    ot = mfma32(t.v0, pf0, ot);
    ot = mfma32(t.v1, pf1, ot);
    ot = mfma32(t.v2, pf2, ot);
    ot = mfma32(t.v3, pf3, ot);
  };

  KV cur = loadKV(0);
#pragma unroll 1
  for (int it = 0; it < 12; ++it) {
    KV nxt = loadKV(it + 1 < 12 ? it + 1 : 11);
    compute(cur, it);
    cur = nxt;
    __builtin_amdgcn_s_barrier();   // keep the 4 waves' K/V streams in lockstep (L1 reuse)
  }

  // store unnormalized O^T partial (bf16) + m/l
  __hip_bfloat16* op = Op + ((size_t)sp * NROW + qrow + cl) * 64 + h * 32 + 4 * hi;
#pragma unroll
  for (int k = 0; k < 4; ++k) {
    uint2 wv = {pkbf(ot[4*k], ot[4*k+1]), pkbf(ot[4*k+2], ot[4*k+3])};
    *(uint2*)(op + 8 * k) = wv;
  }
  if (lane < 32) {
    int mi = ((sp * 24 + nb) * 2 + h) * TT + qtile * 32 + cl;
    Mp[mi] = m;
    Lp[mi] = lsum;
  }
}

// ---------------------------------------------------------------------------
// Fused split-combine + out-projection (MFMA) + residual + LayerNorm.
// Block 256 = 4 waves, 32 rows; wave w owns cols [w*192, +192).
// ---------------------------------------------------------------------------
__global__ __launch_bounds__(256) void oproj_ln_kernel(
    const float* __restrict__ x, const __hip_bfloat16* __restrict__ Op,
    const float* __restrict__ Mp, const float* __restrict__ Lp,
    const __hip_bfloat16* __restrict__ Bo, const float* __restrict__ gamma,
    const float* __restrict__ beta, float* __restrict__ out)
{
  __shared__ float red[4][32][2];
  __shared__ float redf[32][2];
  const int tid = threadIdx.x;
  const int lane = tid & 63, w = tid >> 6;
  const int cl = lane & 31, hi = lane >> 5;
  const int row0 = blockIdx.x * 32;
  const int n = row0 >> 12;
  const int nb = row0 >> 10;
  const int trow = (row0 & 1023) + cl;
  const int MLS = 24 * 2 * TT;

  // combine weights per head
  float wsp[2][NSPLIT];
#pragma unroll
  for (int h = 0; h < 2; ++h) {
    int mi = (nb * 2 + h) * TT + trow;
    float mv[NSPLIT], lv[NSPLIT];
#pragma unroll
    for (int sp = 0; sp < NSPLIT; ++sp) { mv[sp] = Mp[mi + sp * MLS]; lv[sp] = Lp[mi + sp * MLS]; }
    float ms = mv[0];
#pragma unroll
    for (int sp = 1; sp < NSPLIT; ++sp) ms = fmaxf(ms, mv[sp]);
    float den = 0.f;
#pragma unroll
    for (int sp = 0; sp < NSPLIT; ++sp) { wsp[h][sp] = exp2f(mv[sp] - ms); den = fmaf(lv[sp], wsp[h][sp], den); }
    float inv = 1.0f / den;
#pragma unroll
    for (int sp = 0; sp < NSPLIT; ++sp) wsp[h][sp] *= inv;
  }

  // A-frags: combine partials
  u32x4 af[4];
#pragma unroll
  for (int ks = 0; ks < 4; ++ks) {
    int h = ks >> 1;
    size_t off = (size_t)(row0 + cl) * 64 + ks * 16 + hi * 8;
    f32x2 s0 = {}, s1 = {}, s2 = {}, s3 = {};
#pragma unroll
    for (int sp = 0; sp < NSPLIT; ++sp) {
      u32x4 v = *(const u32x4*)(Op + (size_t)sp * NROW * 64 + off);
      float wv = wsp[h][sp];
      s0 += f32x2{b2f(v[0] & 0xffffu), b2f(v[0] >> 16)} * wv;
      s1 += f32x2{b2f(v[1] & 0xffffu), b2f(v[1] >> 16)} * wv;
      s2 += f32x2{b2f(v[2] & 0xffffu), b2f(v[2] >> 16)} * wv;
      s3 += f32x2{b2f(v[3] & 0xffffu), b2f(v[3] >> 16)} * wv;
    }
    af[ks] = u32x4{pkbf(s0.x, s0.y), pkbf(s1.x, s1.y), pkbf(s2.x, s2.y), pkbf(s3.x, s3.y)};
  }

  const __hip_bfloat16* Bp = Bo + ((size_t)n * 768 + w * 192 + cl) * 64 + hi * 8;
  f32x16 acc[6] = {};
#pragma unroll
  for (int ks = 0; ks < 4; ++ks) {
#pragma unroll
    for (int t = 0; t < 6; ++t) {
      u32x4 bb = *(const u32x4*)(Bp + (size_t)(t * 32) * 64 + ks * 16);
      acc[t] = mfma32(af[ks], bb, acc[t]);
    }
  }

  float s1[16], s2[16];
#pragma unroll
  for (int r = 0; r < 16; ++r) { s1[r] = 0.f; s2[r] = 0.f; }
#pragma unroll
  for (int t = 0; t < 6; ++t) {
#pragma unroll
    for (int r = 0; r < 16; ++r) {
      int R = (r & 3) + 8 * (r >> 2) + 4 * hi;
      int col = w * 192 + t * 32 + cl;
      float y = acc[t][r] + x[(size_t)(row0 + R) * 768 + col];
      acc[t][r] = y;
      s1[r] += y;
      s2[r] = fmaf(y, y, s2[r]);
    }
  }
#pragma unroll
  for (int r = 0; r < 16; ++r) {
#pragma unroll
    for (int off = 1; off < 32; off <<= 1) {
      s1[r] += __shfl_xor(s1[r], off);
      s2[r] += __shfl_xor(s2[r], off);
    }
  }
  if (cl == 0) {
#pragma unroll
    for (int r = 0; r < 16; ++r) {
      int R = (r & 3) + 8 * (r >> 2) + 4 * hi;
      red[w][R][0] = s1[r];
      red[w][R][1] = s2[r];
    }
  }
  __syncthreads();
  if (tid < 64) {
    int R = tid & 31, st = tid >> 5;
    redf[R][st] = red[0][R][st] + red[1][R][st] + red[2][R][st] + red[3][R][st];
  }
  __syncthreads();

  float gv[6], bv[6];
#pragma unroll
  for (int t = 0; t < 6; ++t) {
    int col = w * 192 + t * 32 + cl;
    gv[t] = gamma[n * 768 + col];
    bv[t] = beta[n * 768 + col];
  }
#pragma unroll
  for (int r = 0; r < 16; ++r) {
    int R = (r & 3) + 8 * (r >> 2) + 4 * hi;
    float mu = redf[R][0] * (1.0f / 768.0f);
    float var = redf[R][1] * (1.0f / 768.0f) - mu * mu;
    float rs = rsqrtf(var + LNEPS);
#pragma unroll
    for (int t = 0; t < 6; ++t) {
      int col = w * 192 + t * 32 + cl;
      out[(size_t)(row0 + R) * 768 + col] = (acc[t][r] - mu) * rs * gv[t] + bv[t];
    }
  }
}

// ---------------------------------------------------------------------------
extern "C" void kernel_launch(void* const* d_in, const int* in_sizes, int n_in,
                              void* d_out, int out_size, void* d_ws, size_t ws_size,
                              hipStream_t stream) {
  const float* x     = (const float*)d_in[0];
  const float* hist  = (const float*)d_in[1];
  const int*   mask  = (const int*)d_in[2];
  const float* Wq    = (const float*)d_in[3];
  const float* Wk    = (const float*)d_in[4];
  const float* Wv    = (const float*)d_in[5];
  const float* Wo    = (const float*)d_in[6];
  const float* gamma = (const float*)d_in[7];
  const float* beta  = (const float*)d_in[8];
  float* out = (float*)d_out;

  char* ws = (char*)d_ws;
  __hip_bfloat16* Qb  = (__hip_bfloat16*)ws;  ws += (size_t)NROW * II * 2;
  __hip_bfloat16* Kh  = (__hip_bfloat16*)ws;  ws += (size_t)NKVROW * II * 2;
  __hip_bfloat16* Vt2 = (__hip_bfloat16*)ws;  ws += (size_t)NKVROW * II * 2;
  __hip_bfloat16* Op  = (__hip_bfloat16*)ws;  ws += (size_t)NSPLIT * NROW * II * 2;
  float* Mp           = (float*)ws;           ws += (size_t)NSPLIT * 24 * 2 * TT * 4;
  float* Lp           = (float*)ws;           ws += (size_t)NSPLIT * 24 * 2 * TT * 4;
  __hip_bfloat16* Bkv = (__hip_bfloat16*)ws;  ws += (size_t)128 * 768 * 2;
  __hip_bfloat16* Bq  = (__hip_bfloat16*)ws;  ws += (size_t)NDOM * 64 * 768 * 2;
  __hip_bfloat16* Bo  = (__hip_bfloat16*)ws;  ws += (size_t)NDOM * 768 * 64 * 2;
  float* bias2        = (float*)ws;           ws += (size_t)BB * SS * 4;

  const int PREP_N = 128*768 + NDOM*64*768 + NDOM*768*64 + BB*SS;
  prep_kernel<<<(PREP_N + 255) / 256, 256, 0, stream>>>(mask, Wk, Wv, Wq, Wo, Bkv, Bq, Bo, bias2);
  q_gemm_kernel<<<NROW / 128, 256, 0, stream>>>(x, Bq, Qb);
  kv_gemm_kernel<<<NKVROW / 128, 256, 0, stream>>>(hist, Bkv, Kh, Vt2);
  attn_kernel<<<48 * 8 * NSPLIT, 256, 0, stream>>>(Qb, Kh, Vt2, bias2, Op, Mp, Lp);
  oproj_ln_kernel<<<NROW / 32, 256, 0, stream>>>(x, Op, Mp, Lp, Bo, gamma, beta, out);
}

// Round 8
// 230.347 us; speedup vs baseline: 1.3533x; 1.0189x over previous
//
#include <hip/hip_runtime.h>
#include <hip/hip_bf16.h>
#include <math.h>

#define NDOM 6
#define BB 4
#define TT 1024
#define DD 768
#define PP 3
#define HH 2
#define DHH 32
#define II 64
#define SS (PP*TT)        // 3072
#define NROW (NDOM*BB*TT) // 24576
#define NKVROW (NDOM*BB*SS)
#define NSPLIT 4
#define NKVB (NKVROW/128) // 576
#define NQB  (NROW/128)   // 192
#define LNEPS 1e-5f

typedef unsigned int uint;
typedef uint  u32x4  __attribute__((ext_vector_type(4)));
typedef int   i32x2  __attribute__((ext_vector_type(2)));
typedef float f32x2  __attribute__((ext_vector_type(2)));
typedef float f32x4  __attribute__((ext_vector_type(4)));
typedef float f32x16 __attribute__((ext_vector_type(16)));
typedef __bf16 bf16x8 __attribute__((ext_vector_type(8)));

// D = A(32x16) * B(16x32) + C.  A row = lane&31, k = (lane>>5)*8+j.
// B col = lane&31, k = (lane>>5)*8+j.  D: col = lane&31, row=(r&3)+8*(r>>2)+4*(lane>>5).
__device__ __forceinline__ f32x16 mfma32(u32x4 a, u32x4 b, f32x16 c) {
  return __builtin_amdgcn_mfma_f32_32x32x16_bf16(
      __builtin_bit_cast(bf16x8, a), __builtin_bit_cast(bf16x8, b), c, 0, 0, 0);
}

__device__ __forceinline__ uint pkbf(float a, float b) {
  union { __bf16 h[2]; uint u; } v;
  v.h[0] = (__bf16)a; v.h[1] = (__bf16)b;
  return v.u;
}
__device__ __forceinline__ float b2f(uint u16) {
  union { uint i; float f; } v; v.i = u16 << 16; return v.f;
}

// x gets {a_lo | partner's b}, y gets {partner's a | b}  (32-lane halves)
__device__ __forceinline__ void plswap(uint a, uint b, uint& x, uint& y) {
#if __has_builtin(__builtin_amdgcn_permlane32_swap)
  i32x2 r = __builtin_amdgcn_permlane32_swap((int)a, (int)b, false, false);
  x = (uint)r.x; y = (uint)r.y;
#else
  uint sa = __shfl_xor(a, 32), sb = __shfl_xor(b, 32);
  bool h1 = (threadIdx.x & 32) != 0;
  x = h1 ? sb : a;
  y = h1 ? b : sa;
#endif
}

// ---------------------------------------------------------------------------
// Prep: bf16 transposed weights + exp2-domain mask bias.
// ---------------------------------------------------------------------------
__global__ __launch_bounds__(256) void prep_kernel(
    const int* __restrict__ mask, const float* __restrict__ Wk,
    const float* __restrict__ Wv, const float* __restrict__ Wq,
    const float* __restrict__ Wo,
    __hip_bfloat16* __restrict__ Bkv, __hip_bfloat16* __restrict__ Bq,
    __hip_bfloat16* __restrict__ Bo, float* __restrict__ bias2)
{
  int i = blockIdx.x * 256 + threadIdx.x;
  const int N1 = 128 * 768;          // Bkv
  const int N2 = NDOM * 64 * 768;    // Bq
  const int N3 = NDOM * 768 * 64;    // Bo
  if (i < N1) {
    int c = i / 768, k = i % 768;
    float v = (c < 64) ? Wk[k * 64 + c] : Wv[k * 64 + (c - 64)];
    Bkv[i] = __float2bfloat16(v);
  } else if (i < N1 + N2) {
    int j = i - N1;
    int n = j / (64 * 768);
    int rem = j % (64 * 768);
    int c = rem / 768, k = rem % 768;
    Bq[j] = __float2bfloat16(Wq[((size_t)n * 768 + k) * 64 + c]);
  } else if (i < N1 + N2 + N3) {
    int j = i - N1 - N2;
    int n = j / (768 * 64);
    int rem = j % (768 * 64);
    int d = rem / 64, k = rem % 64;
    Bo[j] = __float2bfloat16(Wo[((size_t)n * 64 + k) * 768 + d]);
  } else if (i < N1 + N2 + N3 + BB * SS) {
    int j = i - N1 - N2 - N3;
    int b = j / SS, s = j % SS;
    bias2[j] = (1.0f - (float)mask[b * TT + (s & (TT - 1))]) * (-14426.950408889634f);
  }
}

// ---------------------------------------------------------------------------
// Fused Q + KV projection GEMM.  LDS-staged (coalesced 256B row chunks),
// double-buffered + register-prefetch: loads for chunk k+1 issue right after
// the barrier, hiding HBM latency under chunk k's MFMA/ds_read phase.
// Blocks [0,576): history rows -> Kh (head-split) + Vt2 (sub-blocked).
// Blocks [576,768): x rows -> Q.
// ---------------------------------------------------------------------------
__global__ __launch_bounds__(256) void qkv_gemm_kernel(
    const float* __restrict__ x, const float* __restrict__ hist,
    const __hip_bfloat16* __restrict__ Bkv, const __hip_bfloat16* __restrict__ Bq,
    __hip_bfloat16* __restrict__ Qo, __hip_bfloat16* __restrict__ Kh,
    __hip_bfloat16* __restrict__ Vt2)
{
  __shared__ uint As[2][128 * 32];
  const int tid = threadIdx.x;
  const int lane = tid & 63, w = tid >> 6;
  const int wr = w >> 1, wc = w & 1;
  const int cl = lane & 31, hi = lane >> 5;
  const int r0 = tid >> 3, oct = tid & 7;

  if (blockIdx.x < NKVB) {
    // ---------------- KV branch ----------------
    const int brow = blockIdx.x * 128;
    const int nb = brow / SS;
    const int n = nb >> 2, b = nb & 3;
    const int s0 = brow % SS;
    const int p = s0 / TT, t0 = s0 % TT;
    const float* Asrc = hist + (((size_t)(p * NDOM + n) * BB + b) * TT + t0) * 768;

    float4 a0[4], a1[4];
    auto ldA = [&](int kk) {
#pragma unroll
      for (int g = 0; g < 4; ++g) {
        const float* ap = Asrc + (size_t)(r0 + 32 * g) * 768 + kk * 64 + oct * 8;
        a0[g] = *(const float4*)ap;
        a1[g] = *(const float4*)(ap + 4);
      }
    };

    f32x16 acc00 = {}, acc01 = {}, acc10 = {}, acc11 = {};
    ldA(0);
    for (int kk = 0; kk < 12; ++kk) {
      uint* dst = As[kk & 1];
#pragma unroll
      for (int g = 0; g < 4; ++g) {
        int row = r0 + 32 * g;
        u32x4 pk = {pkbf(a0[g].x, a0[g].y), pkbf(a0[g].z, a0[g].w),
                    pkbf(a1[g].x, a1[g].y), pkbf(a1[g].z, a1[g].w)};
        *(u32x4*)&dst[row * 32 + ((oct ^ (row & 7)) << 2)] = pk;
      }
      __syncthreads();
      if (kk + 1 < 12) ldA(kk + 1);       // prefetch next chunk under compute
#pragma unroll
      for (int ks = 0; ks < 4; ++ks) {
        int kg = kk * 64 + ks * 16 + hi * 8;
        u32x4 b0 = *(const u32x4*)(Bkv + (size_t)(wc * 64 + cl) * 768 + kg);
        u32x4 b1 = *(const u32x4*)(Bkv + (size_t)(wc * 64 + 32 + cl) * 768 + kg);
        int ro0 = wr * 64 + cl;
        int ro1 = ro0 + 32;
        int oc = ks * 2 + hi;
        u32x4 fa0 = *(const u32x4*)&dst[ro0 * 32 + ((oc ^ (ro0 & 7)) << 2)];
        u32x4 fa1 = *(const u32x4*)&dst[ro1 * 32 + ((oc ^ (ro1 & 7)) << 2)];
        acc00 = mfma32(fa0, b0, acc00);
        acc01 = mfma32(fa0, b1, acc01);
        acc10 = mfma32(fa1, b0, acc10);
        acc11 = mfma32(fa1, b1, acc11);
      }
    }

    if (wc == 0) {   // K half: cols 0..63 -> heads 0/1, dims cl
      const size_t base0 = ((size_t)(nb * 2 + 0) * SS);
      const size_t base1 = ((size_t)(nb * 2 + 1) * SS);
#pragma unroll
      for (int r = 0; r < 16; ++r) {
        int rl = (r & 3) + 8 * (r >> 2) + 4 * hi;
        int s  = s0 + wr * 64 + rl;
        Kh[(base0 + s) * 32 + cl]      = __float2bfloat16(acc00[r]);
        Kh[(base1 + s) * 32 + cl]      = __float2bfloat16(acc01[r]);
        Kh[(base0 + s + 32) * 32 + cl] = __float2bfloat16(acc10[r]);
        Kh[(base1 + s + 32) * 32 + cl] = __float2bfloat16(acc11[r]);
      }
    } else {         // V half: cols 64..127 -> Vt2[nb][h][sb][c][8]
#pragma unroll
      for (int k = 0; k < 4; ++k) {
        int sb0 = (s0 + wr * 64 + 8 * k) >> 3;
        int sb1 = sb0 + 4;
        size_t a00 = (((size_t)(nb * 2 + 0) * (SS / 8) + sb0) * 32 + cl) * 8 + 4 * hi;
        size_t a01 = (((size_t)(nb * 2 + 1) * (SS / 8) + sb0) * 32 + cl) * 8 + 4 * hi;
        size_t a10 = (((size_t)(nb * 2 + 0) * (SS / 8) + sb1) * 32 + cl) * 8 + 4 * hi;
        size_t a11 = (((size_t)(nb * 2 + 1) * (SS / 8) + sb1) * 32 + cl) * 8 + 4 * hi;
        *(uint2*)(Vt2 + a00) = uint2{pkbf(acc00[4*k], acc00[4*k+1]), pkbf(acc00[4*k+2], acc00[4*k+3])};
        *(uint2*)(Vt2 + a01) = uint2{pkbf(acc01[4*k], acc01[4*k+1]), pkbf(acc01[4*k+2], acc01[4*k+3])};
        *(uint2*)(Vt2 + a10) = uint2{pkbf(acc10[4*k], acc10[4*k+1]), pkbf(acc10[4*k+2], acc10[4*k+3])};
        *(uint2*)(Vt2 + a11) = uint2{pkbf(acc11[4*k], acc11[4*k+1]), pkbf(acc11[4*k+2], acc11[4*k+3])};
      }
    }
  } else {
    // ---------------- Q branch ----------------
    const int brow = (blockIdx.x - NKVB) * 128;
    const int n = brow >> 12;
    const float* Asrc = x + (size_t)brow * 768;
    const __hip_bfloat16* Bn = Bq + (size_t)n * 64 * 768;

    float4 a0[4], a1[4];
    auto ldA = [&](int kk) {
#pragma unroll
      for (int g = 0; g < 4; ++g) {
        const float* ap = Asrc + (size_t)(r0 + 32 * g) * 768 + kk * 64 + oct * 8;
        a0[g] = *(const float4*)ap;
        a1[g] = *(const float4*)(ap + 4);
      }
    };

    f32x16 acc0 = {}, acc1 = {};
    ldA(0);
    for (int kk = 0; kk < 12; ++kk) {
      uint* dst = As[kk & 1];
#pragma unroll
      for (int g = 0; g < 4; ++g) {
        int row = r0 + 32 * g;
        u32x4 pk = {pkbf(a0[g].x, a0[g].y), pkbf(a0[g].z, a0[g].w),
                    pkbf(a1[g].x, a1[g].y), pkbf(a1[g].z, a1[g].w)};
        *(u32x4*)&dst[row * 32 + ((oct ^ (row & 7)) << 2)] = pk;
      }
      __syncthreads();
      if (kk + 1 < 12) ldA(kk + 1);
#pragma unroll
      for (int ks = 0; ks < 4; ++ks) {
        int kg = kk * 64 + ks * 16 + hi * 8;
        u32x4 b = *(const u32x4*)(Bn + (size_t)(wc * 32 + cl) * 768 + kg);
        int ro0 = wr * 64 + cl;
        int ro1 = ro0 + 32;
        int oc = ks * 2 + hi;
        u32x4 fa0 = *(const u32x4*)&dst[ro0 * 32 + ((oc ^ (ro0 & 7)) << 2)];
        u32x4 fa1 = *(const u32x4*)&dst[ro1 * 32 + ((oc ^ (ro1 & 7)) << 2)];
        acc0 = mfma32(fa0, b, acc0);
        acc1 = mfma32(fa1, b, acc1);
      }
    }
    int c = wc * 32 + cl;
#pragma unroll
    for (int r = 0; r < 16; ++r) {
      int rl = (r & 3) + 8 * (r >> 2) + 4 * hi;
      Qo[(size_t)(brow + wr * 64 + rl) * 64 + c] = __float2bfloat16(acc0[r]);
      Qo[(size_t)(brow + wr * 64 + 32 + rl) * 64 + c] = __float2bfloat16(acc1[r]);
    }
  }
}

// ---------------------------------------------------------------------------
// Flash attention, split-S by 4.  Block = 4 waves sharing one (n,b,h,split):
// wave w owns q-tile tq*4+w; all waves stream the SAME K/V tiles in lockstep
// (raw s_barrier per iter, no LDS) -> L1 broadcast hits.
// ---------------------------------------------------------------------------
struct KV { u32x4 k0, k1, k2, k3, v0, v1, v2, v3; };

__global__ __launch_bounds__(256) void attn_kernel(
    const __hip_bfloat16* __restrict__ Q, const __hip_bfloat16* __restrict__ Kh,
    const __hip_bfloat16* __restrict__ Vt2, const float* __restrict__ bias2,
    __hip_bfloat16* __restrict__ Op, float* __restrict__ Mp, float* __restrict__ Lp)
{
  const int tid = threadIdx.x;
  const int lane = tid & 63, w = tid >> 6;
  const int cl = lane & 31, hi = lane >> 5;
  const int bid = blockIdx.x;
  const int g = bid % 48;            // (n,b,h) group -> fixed XCD (48 % 8 == 0)
  const int rest = bid / 48;         // 0..31
  const int sp = rest >> 3;          // split 0..3
  const int tq = rest & 7;           // q super-tile 0..7
  const int qtile = tq * 4 + w;      // 0..31
  const int h = g & 1, nb = g >> 1;
  const int b = nb & 3;
  const int qrow = nb * TT + qtile * 32;
  const int sbase = sp * (SS / NSPLIT);   // 768 keys per split

  const __hip_bfloat16* Qp = Q + (size_t)(qrow + cl) * 64 + h * 32 + hi * 8;
  u32x4 qf0 = *(const u32x4*)Qp;
  u32x4 qf1 = *(const u32x4*)(Qp + 16);

  const __hip_bfloat16* Kp = Kh + ((size_t)(nb * 2 + h) * SS + sbase) * 32;
  const __hip_bfloat16* Vp = Vt2 + (size_t)(nb * 2 + h) * SS * 32 + (size_t)sbase * 32;
  const float* Bp = bias2 + b * SS + sbase + hi * 4;

  const float scale2 = 0.17677669529663687f * 1.4426950408889634f;
  const f32x2 sc2 = {scale2, scale2};

  f32x16 ot = {};
  float m = -1e30f, lsum = 0.f;

  auto loadKV = [&](int it) {
    KV t;
    const __hip_bfloat16* kp = Kp + (size_t)it * 64 * 32;
    t.k0 = *(const u32x4*)(kp + cl * 32 + hi * 8);
    t.k1 = *(const u32x4*)(kp + cl * 32 + 16 + hi * 8);
    t.k2 = *(const u32x4*)(kp + 1024 + cl * 32 + hi * 8);
    t.k3 = *(const u32x4*)(kp + 1024 + cl * 32 + 16 + hi * 8);
    const __hip_bfloat16* vp = Vp + (size_t)it * 64 * 32;
    t.v0 = *(const u32x4*)(vp + ((0 * 2 + hi) * 32 + cl) * 8);
    t.v1 = *(const u32x4*)(vp + ((1 * 2 + hi) * 32 + cl) * 8);
    t.v2 = *(const u32x4*)(vp + ((2 * 2 + hi) * 32 + cl) * 8);
    t.v3 = *(const u32x4*)(vp + ((3 * 2 + hi) * 32 + cl) * 8);
    return t;
  };

  auto compute = [&](const KV& t, int it) {
    f32x16 pz0 = {}, pz1 = {};
    pz0 = mfma32(t.k0, qf0, pz0);
    pz0 = mfma32(t.k1, qf1, pz0);
    pz1 = mfma32(t.k2, qf0, pz1);
    pz1 = mfma32(t.k3, qf1, pz1);
    const float* bp = Bp + it * 64;
    f32x4 b4[8];
#pragma unroll
    for (int q = 0; q < 8; ++q) b4[q] = *(const f32x4*)(bp + 8 * q);
    f32x2 p2[16];
#pragma unroll
    for (int i = 0; i < 8; ++i) {
      f32x4 bq0 = b4[i >> 1];
      f32x4 bq1 = b4[4 + (i >> 1)];
      f32x2 bv0 = (i & 1) ? f32x2{bq0.z, bq0.w} : f32x2{bq0.x, bq0.y};
      f32x2 bv1 = (i & 1) ? f32x2{bq1.z, bq1.w} : f32x2{bq1.x, bq1.y};
      p2[i]     = f32x2{pz0[2*i], pz0[2*i+1]} * sc2 + bv0;
      p2[8 + i] = f32x2{pz1[2*i], pz1[2*i+1]} * sc2 + bv1;
    }
    f32x2 mx = p2[0];
#pragma unroll
    for (int i = 1; i < 16; ++i) {
      mx.x = fmaxf(mx.x, p2[i].x);
      mx.y = fmaxf(mx.y, p2[i].y);
    }
    float tm = fmaxf(mx.x, mx.y);
    tm = fmaxf(tm, __shfl_xor(tm, 32));
    if (!__all(tm - m <= 8.f)) {       // defer-max
      float mn = fmaxf(m, tm);
      float f = exp2f(m - mn);
#pragma unroll
      for (int i = 0; i < 16; ++i) ot[i] *= f;
      lsum *= f;
      m = mn;
    }
    const f32x2 m2 = {m, m};
    f32x2 s2 = {0.f, 0.f};
#pragma unroll
    for (int i = 0; i < 16; ++i) {
      f32x2 d = p2[i] - m2;
      f32x2 e = {exp2f(d.x), exp2f(d.y)};
      p2[i] = e;
      s2 += e;
    }
    float ts = s2.x + s2.y;
    ts += __shfl_xor(ts, 32);
    lsum += ts;
    // P -> bf16 B-frags via permlane32_swap
    uint cv[16];
#pragma unroll
    for (int i = 0; i < 16; ++i) cv[i] = pkbf(p2[i].x, p2[i].y);
    u32x4 pf0, pf1, pf2, pf3;
    {
      uint x0, y0, x1, y1;
      plswap(cv[0], cv[2],  x0, y0); plswap(cv[1], cv[3],  x1, y1);
      pf0 = u32x4{x0, x1, y0, y1};
      plswap(cv[4], cv[6],  x0, y0); plswap(cv[5], cv[7],  x1, y1);
      pf1 = u32x4{x0, x1, y0, y1};
      plswap(cv[8], cv[10], x0, y0); plswap(cv[9], cv[11], x1, y1);
      pf2 = u32x4{x0, x1, y0, y1};
      plswap(cv[12], cv[14], x0, y0); plswap(cv[13], cv[15], x1, y1);
      pf3 = u32x4{x0, x1, y0, y1};
    }
    ot = mfma32(t.v0, pf0, ot);
    ot = mfma32(t.v1, pf1, ot);
    ot = mfma32(t.v2, pf2, ot);
    ot = mfma32(t.v3, pf3, ot);
  };

  KV cur = loadKV(0);
#pragma unroll 1
  for (int it = 0; it < 12; ++it) {
    KV nxt = loadKV(it + 1 < 12 ? it + 1 : 11);
    compute(cur, it);
    cur = nxt;
    __builtin_amdgcn_s_barrier();   // keep the 4 waves' K/V streams in lockstep (L1 reuse)
  }

  // store unnormalized O^T partial (bf16) + m/l
  __hip_bfloat16* op = Op + ((size_t)sp * NROW + qrow + cl) * 64 + h * 32 + 4 * hi;
#pragma unroll
  for (int k = 0; k < 4; ++k) {
    uint2 wv = {pkbf(ot[4*k], ot[4*k+1]), pkbf(ot[4*k+2], ot[4*k+3])};
    *(uint2*)(op + 8 * k) = wv;
  }
  if (lane < 32) {
    int mi = ((sp * 24 + nb) * 2 + h) * TT + qtile * 32 + cl;
    Mp[mi] = m;
    Lp[mi] = lsum;
  }
}

// ---------------------------------------------------------------------------
// Fused split-combine + out-projection (MFMA) + residual + LayerNorm.
// Block 256 = 4 waves, 32 rows; wave w owns cols [w*192, +192).
// ---------------------------------------------------------------------------
__global__ __launch_bounds__(256) void oproj_ln_kernel(
    const float* __restrict__ x, const __hip_bfloat16* __restrict__ Op,
    const float* __restrict__ Mp, const float* __restrict__ Lp,
    const __hip_bfloat16* __restrict__ Bo, const float* __restrict__ gamma,
    const float* __restrict__ beta, float* __restrict__ out)
{
  __shared__ float red[4][32][2];
  __shared__ float redf[32][2];
  const int tid = threadIdx.x;
  const int lane = tid & 63, w = tid >> 6;
  const int cl = lane & 31, hi = lane >> 5;
  const int row0 = blockIdx.x * 32;
  const int n = row0 >> 12;
  const int nb = row0 >> 10;
  const int trow = (row0 & 1023) + cl;
  const int MLS = 24 * 2 * TT;

  // combine weights per head
  float wsp[2][NSPLIT];
#pragma unroll
  for (int h = 0; h < 2; ++h) {
    int mi = (nb * 2 + h) * TT + trow;
    float mv[NSPLIT], lv[NSPLIT];
#pragma unroll
    for (int sp = 0; sp < NSPLIT; ++sp) { mv[sp] = Mp[mi + sp * MLS]; lv[sp] = Lp[mi + sp * MLS]; }
    float ms = mv[0];
#pragma unroll
    for (int sp = 1; sp < NSPLIT; ++sp) ms = fmaxf(ms, mv[sp]);
    float den = 0.f;
#pragma unroll
    for (int sp = 0; sp < NSPLIT; ++sp) { wsp[h][sp] = exp2f(mv[sp] - ms); den = fmaf(lv[sp], wsp[h][sp], den); }
    float inv = 1.0f / den;
#pragma unroll
    for (int sp = 0; sp < NSPLIT; ++sp) wsp[h][sp] *= inv;
  }

  // A-frags: combine partials
  u32x4 af[4];
#pragma unroll
  for (int ks = 0; ks < 4; ++ks) {
    int h = ks >> 1;
    size_t off = (size_t)(row0 + cl) * 64 + ks * 16 + hi * 8;
    f32x2 s0 = {}, s1 = {}, s2 = {}, s3 = {};
#pragma unroll
    for (int sp = 0; sp < NSPLIT; ++sp) {
      u32x4 v = *(const u32x4*)(Op + (size_t)sp * NROW * 64 + off);
      float wv = wsp[h][sp];
      s0 += f32x2{b2f(v[0] & 0xffffu), b2f(v[0] >> 16)} * wv;
      s1 += f32x2{b2f(v[1] & 0xffffu), b2f(v[1] >> 16)} * wv;
      s2 += f32x2{b2f(v[2] & 0xffffu), b2f(v[2] >> 16)} * wv;
      s3 += f32x2{b2f(v[3] & 0xffffu), b2f(v[3] >> 16)} * wv;
    }
    af[ks] = u32x4{pkbf(s0.x, s0.y), pkbf(s1.x, s1.y), pkbf(s2.x, s2.y), pkbf(s3.x, s3.y)};
  }

  const __hip_bfloat16* Bp = Bo + ((size_t)n * 768 + w * 192 + cl) * 64 + hi * 8;
  f32x16 acc[6] = {};
#pragma unroll
  for (int ks = 0; ks < 4; ++ks) {
#pragma unroll
    for (int t = 0; t < 6; ++t) {
      u32x4 bb = *(const u32x4*)(Bp + (size_t)(t * 32) * 64 + ks * 16);
      acc[t] = mfma32(af[ks], bb, acc[t]);
    }
  }

  float s1[16], s2[16];
#pragma unroll
  for (int r = 0; r < 16; ++r) { s1[r] = 0.f; s2[r] = 0.f; }
#pragma unroll
  for (int t = 0; t < 6; ++t) {
#pragma unroll
    for (int r = 0; r < 16; ++r) {
      int R = (r & 3) + 8 * (r >> 2) + 4 * hi;
      int col = w * 192 + t * 32 + cl;
      float y = acc[t][r] + x[(size_t)(row0 + R) * 768 + col];
      acc[t][r] = y;
      s1[r] += y;
      s2[r] = fmaf(y, y, s2[r]);
    }
  }
#pragma unroll
  for (int r = 0; r < 16; ++r) {
#pragma unroll
    for (int off = 1; off < 32; off <<= 1) {
      s1[r] += __shfl_xor(s1[r], off);
      s2[r] += __shfl_xor(s2[r], off);
    }
  }
  if (cl == 0) {
#pragma unroll
    for (int r = 0; r < 16; ++r) {
      int R = (r & 3) + 8 * (r >> 2) + 4 * hi;
      red[w][R][0] = s1[r];
      red[w][R][1] = s2[r];
    }
  }
  __syncthreads();
  if (tid < 64) {
    int R = tid & 31, st = tid >> 5;
    redf[R][st] = red[0][R][st] + red[1][R][st] + red[2][R][st] + red[3][R][st];
  }
  __syncthreads();

  float gv[6], bv[6];
#pragma unroll
  for (int t = 0; t < 6; ++t) {
    int col = w * 192 + t * 32 + cl;
    gv[t] = gamma[n * 768 + col];
    bv[t] = beta[n * 768 + col];
  }
#pragma unroll
  for (int r = 0; r < 16; ++r) {
    int R = (r & 3) + 8 * (r >> 2) + 4 * hi;
    float mu = redf[R][0] * (1.0f / 768.0f);
    float var = redf[R][1] * (1.0f / 768.0f) - mu * mu;
    float rs = rsqrtf(var + LNEPS);
#pragma unroll
    for (int t = 0; t < 6; ++t) {
      int col = w * 192 + t * 32 + cl;
      out[(size_t)(row0 + R) * 768 + col] = (acc[t][r] - mu) * rs * gv[t] + bv[t];
    }
  }
}

// ---------------------------------------------------------------------------
extern "C" void kernel_launch(void* const* d_in, const int* in_sizes, int n_in,
                              void* d_out, int out_size, void* d_ws, size_t ws_size,
                              hipStream_t stream) {
  const float* x     = (const float*)d_in[0];
  const float* hist  = (const float*)d_in[1];
  const int*   mask  = (const int*)d_in[2];
  const float* Wq    = (const float*)d_in[3];
  const float* Wk    = (const float*)d_in[4];
  const float* Wv    = (const float*)d_in[5];
  const float* Wo    = (const float*)d_in[6];
  const float* gamma = (const float*)d_in[7];
  const float* beta  = (const float*)d_in[8];
  float* out = (float*)d_out;

  char* ws = (char*)d_ws;
  __hip_bfloat16* Qb  = (__hip_bfloat16*)ws;  ws += (size_t)NROW * II * 2;
  __hip_bfloat16* Kh  = (__hip_bfloat16*)ws;  ws += (size_t)NKVROW * II * 2;
  __hip_bfloat16* Vt2 = (__hip_bfloat16*)ws;  ws += (size_t)NKVROW * II * 2;
  __hip_bfloat16* Op  = (__hip_bfloat16*)ws;  ws += (size_t)NSPLIT * NROW * II * 2;
  float* Mp           = (float*)ws;           ws += (size_t)NSPLIT * 24 * 2 * TT * 4;
  float* Lp           = (float*)ws;           ws += (size_t)NSPLIT * 24 * 2 * TT * 4;
  __hip_bfloat16* Bkv = (__hip_bfloat16*)ws;  ws += (size_t)128 * 768 * 2;
  __hip_bfloat16* Bq  = (__hip_bfloat16*)ws;  ws += (size_t)NDOM * 64 * 768 * 2;
  __hip_bfloat16* Bo  = (__hip_bfloat16*)ws;  ws += (size_t)NDOM * 768 * 64 * 2;
  float* bias2        = (float*)ws;           ws += (size_t)BB * SS * 4;

  const int PREP_N = 128*768 + NDOM*64*768 + NDOM*768*64 + BB*SS;
  prep_kernel<<<(PREP_N + 255) / 256, 256, 0, stream>>>(mask, Wk, Wv, Wq, Wo, Bkv, Bq, Bo, bias2);
  qkv_gemm_kernel<<<NKVB + NQB, 256, 0, stream>>>(x, hist, Bkv, Bq, Qb, Kh, Vt2);
  attn_kernel<<<48 * 8 * NSPLIT, 256, 0, stream>>>(Qb, Kh, Vt2, bias2, Op, Mp, Lp);
  oproj_ln_kernel<<<NROW / 32, 256, 0, stream>>>(x, Op, Mp, Lp, Bo, gamma, beta, out);
}

// Round 9
// 219.200 us; speedup vs baseline: 1.4221x; 1.0509x over previous
//
#include <hip/hip_runtime.h>
#include <hip/hip_bf16.h>
#include <math.h>

#define NDOM 6
#define BB 4
#define TT 1024
#define DD 768
#define PP 3
#define HH 2
#define DHH 32
#define II 64
#define SS (PP*TT)        // 3072
#define NROW (NDOM*BB*TT) // 24576
#define NKVROW (NDOM*BB*SS)
#define NSPLIT 4
#define NKVB (NKVROW/64)  // 1152
#define NQB  (NROW/64)    // 384
#define LNEPS 1e-5f

typedef unsigned int uint;
typedef uint  u32x4  __attribute__((ext_vector_type(4)));
typedef int   i32x2  __attribute__((ext_vector_type(2)));
typedef float f32x2  __attribute__((ext_vector_type(2)));
typedef float f32x4  __attribute__((ext_vector_type(4)));
typedef float f32x16 __attribute__((ext_vector_type(16)));
typedef __bf16 bf16x8 __attribute__((ext_vector_type(8)));

// D = A(32x16) * B(16x32) + C.  A row = lane&31, k = (lane>>5)*8+j.
// B col = lane&31, k = (lane>>5)*8+j.  D: col = lane&31, row=(r&3)+8*(r>>2)+4*(lane>>5).
__device__ __forceinline__ f32x16 mfma32(u32x4 a, u32x4 b, f32x16 c) {
  return __builtin_amdgcn_mfma_f32_32x32x16_bf16(
      __builtin_bit_cast(bf16x8, a), __builtin_bit_cast(bf16x8, b), c, 0, 0, 0);
}

__device__ __forceinline__ uint pkbf(float a, float b) {
  union { __bf16 h[2]; uint u; } v;
  v.h[0] = (__bf16)a; v.h[1] = (__bf16)b;
  return v.u;
}
__device__ __forceinline__ float b2f(uint u16) {
  union { uint i; float f; } v; v.i = u16 << 16; return v.f;
}

// x gets {a_lo | partner's b}, y gets {partner's a | b}  (32-lane halves)
__device__ __forceinline__ void plswap(uint a, uint b, uint& x, uint& y) {
#if __has_builtin(__builtin_amdgcn_permlane32_swap)
  i32x2 r = __builtin_amdgcn_permlane32_swap((int)a, (int)b, false, false);
  x = (uint)r.x; y = (uint)r.y;
#else
  uint sa = __shfl_xor(a, 32), sb = __shfl_xor(b, 32);
  bool h1 = (threadIdx.x & 32) != 0;
  x = h1 ? sb : a;
  y = h1 ? b : sa;
#endif
}

// ---------------------------------------------------------------------------
// Prep: bf16 transposed weights + exp2-domain mask bias.
// ---------------------------------------------------------------------------
__global__ __launch_bounds__(256) void prep_kernel(
    const int* __restrict__ mask, const float* __restrict__ Wk,
    const float* __restrict__ Wv, const float* __restrict__ Wq,
    const float* __restrict__ Wo,
    __hip_bfloat16* __restrict__ Bkv, __hip_bfloat16* __restrict__ Bq,
    __hip_bfloat16* __restrict__ Bo, float* __restrict__ bias2)
{
  int i = blockIdx.x * 256 + threadIdx.x;
  const int N1 = 128 * 768;          // Bkv
  const int N2 = NDOM * 64 * 768;    // Bq
  const int N3 = NDOM * 768 * 64;    // Bo
  if (i < N1) {
    int c = i / 768, k = i % 768;
    float v = (c < 64) ? Wk[k * 64 + c] : Wv[k * 64 + (c - 64)];
    Bkv[i] = __float2bfloat16(v);
  } else if (i < N1 + N2) {
    int j = i - N1;
    int n = j / (64 * 768);
    int rem = j % (64 * 768);
    int c = rem / 768, k = rem % 768;
    Bq[j] = __float2bfloat16(Wq[((size_t)n * 768 + k) * 64 + c]);
  } else if (i < N1 + N2 + N3) {
    int j = i - N1 - N2;
    int n = j / (768 * 64);
    int rem = j % (768 * 64);
    int d = rem / 64, k = rem % 64;
    Bo[j] = __float2bfloat16(Wo[((size_t)n * 64 + k) * 768 + d]);
  } else if (i < N1 + N2 + N3 + BB * SS) {
    int j = i - N1 - N2 - N3;
    int b = j / SS, s = j % SS;
    bias2[j] = (1.0f - (float)mask[b * TT + (s & (TT - 1))]) * (-14426.950408889634f);
  }
}

// ---------------------------------------------------------------------------
// Fused Q + KV projection GEMM, BM=64 (1536 blocks -> 6 blocks/CU for
// latency hiding).  LDS-staged (coalesced 256B row chunks), double-buffered
// + register prefetch of the next chunk under the current chunk's compute.
// Blocks [0,1152): history rows -> Kh (head-split) + Vt2 (sub-blocked).
// Blocks [1152,1536): x rows -> Q.
// ---------------------------------------------------------------------------
__global__ __launch_bounds__(256) void qkv_gemm_kernel(
    const float* __restrict__ x, const float* __restrict__ hist,
    const __hip_bfloat16* __restrict__ Bkv, const __hip_bfloat16* __restrict__ Bq,
    __hip_bfloat16* __restrict__ Qo, __hip_bfloat16* __restrict__ Kh,
    __hip_bfloat16* __restrict__ Vt2)
{
  __shared__ uint As[2][64 * 32];
  const int tid = threadIdx.x;
  const int lane = tid & 63, w = tid >> 6;
  const int cl = lane & 31, hi = lane >> 5;
  const int r0 = tid >> 3, oct = tid & 7;   // r0: 0..31, oct: 0..7

  if (blockIdx.x < NKVB) {
    // ---------------- KV branch: wave w -> col group w*32 (K h0,K h1,V h0,V h1)
    const int brow = blockIdx.x * 64;
    const int nb = brow / SS;
    const int n = nb >> 2, b = nb & 3;
    const int s0 = brow % SS;
    const int p = s0 / TT, t0 = s0 % TT;    // 64 | 1024, block stays in one p
    const float* Asrc = hist + (((size_t)(p * NDOM + n) * BB + b) * TT + t0) * 768;

    float4 a0[2], a1[2];
    auto ldA = [&](int kk) {
#pragma unroll
      for (int g = 0; g < 2; ++g) {
        const float* ap = Asrc + (size_t)(r0 + 32 * g) * 768 + kk * 64 + oct * 8;
        a0[g] = *(const float4*)ap;
        a1[g] = *(const float4*)(ap + 4);
      }
    };

    f32x16 acc0 = {}, acc1 = {};
    ldA(0);
    for (int kk = 0; kk < 12; ++kk) {
      uint* dst = As[kk & 1];
#pragma unroll
      for (int g = 0; g < 2; ++g) {
        int row = r0 + 32 * g;
        u32x4 pk = {pkbf(a0[g].x, a0[g].y), pkbf(a0[g].z, a0[g].w),
                    pkbf(a1[g].x, a1[g].y), pkbf(a1[g].z, a1[g].w)};
        *(u32x4*)&dst[row * 32 + ((oct ^ (row & 7)) << 2)] = pk;
      }
      __syncthreads();
      if (kk + 1 < 12) ldA(kk + 1);       // prefetch next chunk under compute
#pragma unroll
      for (int ks = 0; ks < 4; ++ks) {
        int kg = kk * 64 + ks * 16 + hi * 8;
        u32x4 bfrag = *(const u32x4*)(Bkv + (size_t)(w * 32 + cl) * 768 + kg);
        int oc = ks * 2 + hi;
        int ro0 = cl, ro1 = cl + 32;
        u32x4 fa0 = *(const u32x4*)&dst[ro0 * 32 + ((oc ^ (ro0 & 7)) << 2)];
        u32x4 fa1 = *(const u32x4*)&dst[ro1 * 32 + ((oc ^ (ro1 & 7)) << 2)];
        acc0 = mfma32(fa0, bfrag, acc0);
        acc1 = mfma32(fa1, bfrag, acc1);
      }
    }

    if (w < 2) {     // K cols: head w, dim cl
      const size_t base = (size_t)(nb * 2 + w) * SS;
#pragma unroll
      for (int r = 0; r < 16; ++r) {
        int rl = (r & 3) + 8 * (r >> 2) + 4 * hi;
        Kh[(base + s0 + rl) * 32 + cl]      = __float2bfloat16(acc0[r]);
        Kh[(base + s0 + 32 + rl) * 32 + cl] = __float2bfloat16(acc1[r]);
      }
    } else {         // V cols: head w-2 -> Vt2[nb][h][sb][c][8]
      const int h = w - 2;
#pragma unroll
      for (int k = 0; k < 4; ++k) {
        int sb0 = (s0 + 8 * k) >> 3;
        int sb1 = sb0 + 4;
        size_t A0 = (((size_t)(nb * 2 + h) * (SS / 8) + sb0) * 32 + cl) * 8 + 4 * hi;
        size_t A1 = (((size_t)(nb * 2 + h) * (SS / 8) + sb1) * 32 + cl) * 8 + 4 * hi;
        *(uint2*)(Vt2 + A0) = uint2{pkbf(acc0[4*k], acc0[4*k+1]), pkbf(acc0[4*k+2], acc0[4*k+3])};
        *(uint2*)(Vt2 + A1) = uint2{pkbf(acc1[4*k], acc1[4*k+1]), pkbf(acc1[4*k+2], acc1[4*k+3])};
      }
    }
  } else {
    // ---------------- Q branch: wave (wr,wc) -> 32 rows x 32 cols
    const int brow = (blockIdx.x - NKVB) * 64;
    const int n = brow >> 12;
    const int wr = w >> 1, wc = w & 1;
    const float* Asrc = x + (size_t)brow * 768;
    const __hip_bfloat16* Bn = Bq + (size_t)n * 64 * 768;

    float4 a0[2], a1[2];
    auto ldA = [&](int kk) {
#pragma unroll
      for (int g = 0; g < 2; ++g) {
        const float* ap = Asrc + (size_t)(r0 + 32 * g) * 768 + kk * 64 + oct * 8;
        a0[g] = *(const float4*)ap;
        a1[g] = *(const float4*)(ap + 4);
      }
    };

    f32x16 acc = {};
    ldA(0);
    for (int kk = 0; kk < 12; ++kk) {
      uint* dst = As[kk & 1];
#pragma unroll
      for (int g = 0; g < 2; ++g) {
        int row = r0 + 32 * g;
        u32x4 pk = {pkbf(a0[g].x, a0[g].y), pkbf(a0[g].z, a0[g].w),
                    pkbf(a1[g].x, a1[g].y), pkbf(a1[g].z, a1[g].w)};
        *(u32x4*)&dst[row * 32 + ((oct ^ (row & 7)) << 2)] = pk;
      }
      __syncthreads();
      if (kk + 1 < 12) ldA(kk + 1);
#pragma unroll
      for (int ks = 0; ks < 4; ++ks) {
        int kg = kk * 64 + ks * 16 + hi * 8;
        u32x4 bfrag = *(const u32x4*)(Bn + (size_t)(wc * 32 + cl) * 768 + kg);
        int oc = ks * 2 + hi;
        int ro = wr * 32 + cl;
        u32x4 fa = *(const u32x4*)&dst[ro * 32 + ((oc ^ (ro & 7)) << 2)];
        acc = mfma32(fa, bfrag, acc);
      }
    }
    int c = wc * 32 + cl;
#pragma unroll
    for (int r = 0; r < 16; ++r) {
      int rl = (r & 3) + 8 * (r >> 2) + 4 * hi;
      Qo[(size_t)(brow + wr * 32 + rl) * 64 + c] = __float2bfloat16(acc[r]);
    }
  }
}

// ---------------------------------------------------------------------------
// Flash attention, split-S by 4.  Block = 4 waves sharing one (n,b,h,split):
// wave w owns q-tile tq*4+w; all waves stream the SAME K/V tiles in lockstep
// (raw s_barrier per iter, no LDS) -> L1 broadcast hits.
// ---------------------------------------------------------------------------
struct KV { u32x4 k0, k1, k2, k3, v0, v1, v2, v3; };

__global__ __launch_bounds__(256) void attn_kernel(
    const __hip_bfloat16* __restrict__ Q, const __hip_bfloat16* __restrict__ Kh,
    const __hip_bfloat16* __restrict__ Vt2, const float* __restrict__ bias2,
    __hip_bfloat16* __restrict__ Op, float* __restrict__ Mp, float* __restrict__ Lp)
{
  const int tid = threadIdx.x;
  const int lane = tid & 63, w = tid >> 6;
  const int cl = lane & 31, hi = lane >> 5;
  const int bid = blockIdx.x;
  const int g = bid % 48;            // (n,b,h) group -> fixed XCD (48 % 8 == 0)
  const int rest = bid / 48;         // 0..31
  const int sp = rest >> 3;          // split 0..3
  const int tq = rest & 7;           // q super-tile 0..7
  const int qtile = tq * 4 + w;      // 0..31
  const int h = g & 1, nb = g >> 1;
  const int b = nb & 3;
  const int qrow = nb * TT + qtile * 32;
  const int sbase = sp * (SS / NSPLIT);   // 768 keys per split

  const __hip_bfloat16* Qp = Q + (size_t)(qrow + cl) * 64 + h * 32 + hi * 8;
  u32x4 qf0 = *(const u32x4*)Qp;
  u32x4 qf1 = *(const u32x4*)(Qp + 16);

  const __hip_bfloat16* Kp = Kh + ((size_t)(nb * 2 + h) * SS + sbase) * 32;
  const __hip_bfloat16* Vp = Vt2 + (size_t)(nb * 2 + h) * SS * 32 + (size_t)sbase * 32;
  const float* Bp = bias2 + b * SS + sbase + hi * 4;

  const float scale2 = 0.17677669529663687f * 1.4426950408889634f;
  const f32x2 sc2 = {scale2, scale2};

  f32x16 ot = {};
  float m = -1e30f, lsum = 0.f;

  auto loadKV = [&](int it) {
    KV t;
    const __hip_bfloat16* kp = Kp + (size_t)it * 64 * 32;
    t.k0 = *(const u32x4*)(kp + cl * 32 + hi * 8);
    t.k1 = *(const u32x4*)(kp + cl * 32 + 16 + hi * 8);
    t.k2 = *(const u32x4*)(kp + 1024 + cl * 32 + hi * 8);
    t.k3 = *(const u32x4*)(kp + 1024 + cl * 32 + 16 + hi * 8);
    const __hip_bfloat16* vp = Vp + (size_t)it * 64 * 32;
    t.v0 = *(const u32x4*)(vp + ((0 * 2 + hi) * 32 + cl) * 8);
    t.v1 = *(const u32x4*)(vp + ((1 * 2 + hi) * 32 + cl) * 8);
    t.v2 = *(const u32x4*)(vp + ((2 * 2 + hi) * 32 + cl) * 8);
    t.v3 = *(const u32x4*)(vp + ((3 * 2 + hi) * 32 + cl) * 8);
    return t;
  };

  auto compute = [&](const KV& t, int it) {
    f32x16 pz0 = {}, pz1 = {};
    pz0 = mfma32(t.k0, qf0, pz0);
    pz0 = mfma32(t.k1, qf1, pz0);
    pz1 = mfma32(t.k2, qf0, pz1);
    pz1 = mfma32(t.k3, qf1, pz1);
    const float* bp = Bp + it * 64;
    f32x4 b4[8];
#pragma unroll
    for (int q = 0; q < 8; ++q) b4[q] = *(const f32x4*)(bp + 8 * q);
    f32x2 p2[16];
#pragma unroll
    for (int i = 0; i < 8; ++i) {
      f32x4 bq0 = b4[i >> 1];
      f32x4 bq1 = b4[4 + (i >> 1)];
      f32x2 bv0 = (i & 1) ? f32x2{bq0.z, bq0.w} : f32x2{bq0.x, bq0.y};
      f32x2 bv1 = (i & 1) ? f32x2{bq1.z, bq1.w} : f32x2{bq1.x, bq1.y};
      p2[i]     = f32x2{pz0[2*i], pz0[2*i+1]} * sc2 + bv0;
      p2[8 + i] = f32x2{pz1[2*i], pz1[2*i+1]} * sc2 + bv1;
    }
    f32x2 mx = p2[0];
#pragma unroll
    for (int i = 1; i < 16; ++i) {
      mx.x = fmaxf(mx.x, p2[i].x);
      mx.y = fmaxf(mx.y, p2[i].y);
    }
    float tm = fmaxf(mx.x, mx.y);
    tm = fmaxf(tm, __shfl_xor(tm, 32));
    if (!__all(tm - m <= 8.f)) {       // defer-max
      float mn = fmaxf(m, tm);
      float f = exp2f(m - mn);
#pragma unroll
      for (int i = 0; i < 16; ++i) ot[i] *= f;
      lsum *= f;
      m = mn;
    }
    const f32x2 m2 = {m, m};
    f32x2 s2 = {0.f, 0.f};
#pragma unroll
    for (int i = 0; i < 16; ++i) {
      f32x2 d = p2[i] - m2;
      f32x2 e = {exp2f(d.x), exp2f(d.y)};
      p2[i] = e;
      s2 += e;
    }
    float ts = s2.x + s2.y;
    ts += __shfl_xor(ts, 32);
    lsum += ts;
    // P -> bf16 B-frags via permlane32_swap
    uint cv[16];
#pragma unroll
    for (int i = 0; i < 16; ++i) cv[i] = pkbf(p2[i].x, p2[i].y);
    u32x4 pf0, pf1, pf2, pf3;
    {
      uint x0, y0, x1, y1;
      plswap(cv[0], cv[2],  x0, y0); plswap(cv[1], cv[3],  x1, y1);
      pf0 = u32x4{x0, x1, y0, y1};
      plswap(cv[4], cv[6],  x0, y0); plswap(cv[5], cv[7],  x1, y1);
      pf1 = u32x4{x0, x1, y0, y1};
      plswap(cv[8], cv[10], x0, y0); plswap(cv[9], cv[11], x1, y1);
      pf2 = u32x4{x0, x1, y0, y1};
      plswap(cv[12], cv[14], x0, y0); plswap(cv[13], cv[15], x1, y1);
      pf3 = u32x4{x0, x1, y0, y1};
    }
    ot = mfma32(t.v0, pf0, ot);
    ot = mfma32(t.v1, pf1, ot);
    ot = mfma32(t.v2, pf2, ot);
    ot = mfma32(t.v3, pf3, ot);
  };

  KV cur = loadKV(0);
#pragma unroll 1
  for (int it = 0; it < 12; ++it) {
    KV nxt = loadKV(it + 1 < 12 ? it + 1 : 11);
    compute(cur, it);
    cur = nxt;
    __builtin_amdgcn_s_barrier();   // keep the 4 waves' K/V streams in lockstep (L1 reuse)
  }

  // store unnormalized O^T partial (bf16) + m/l
  __hip_bfloat16* op = Op + ((size_t)sp * NROW + qrow + cl) * 64 + h * 32 + 4 * hi;
#pragma unroll
  for (int k = 0; k < 4; ++k) {
    uint2 wv = {pkbf(ot[4*k], ot[4*k+1]), pkbf(ot[4*k+2], ot[4*k+3])};
    *(uint2*)(op + 8 * k) = wv;
  }
  if (lane < 32) {
    int mi = ((sp * 24 + nb) * 2 + h) * TT + qtile * 32 + cl;
    Mp[mi] = m;
    Lp[mi] = lsum;
  }
}

// ---------------------------------------------------------------------------
// Fused split-combine + out-projection (MFMA) + residual + LayerNorm.
// Block 256 = 4 waves, 32 rows; wave w owns cols [w*192, +192).
// ---------------------------------------------------------------------------
__global__ __launch_bounds__(256) void oproj_ln_kernel(
    const float* __restrict__ x, const __hip_bfloat16* __restrict__ Op,
    const float* __restrict__ Mp, const float* __restrict__ Lp,
    const __hip_bfloat16* __restrict__ Bo, const float* __restrict__ gamma,
    const float* __restrict__ beta, float* __restrict__ out)
{
  __shared__ float red[4][32][2];
  __shared__ float redf[32][2];
  const int tid = threadIdx.x;
  const int lane = tid & 63, w = tid >> 6;
  const int cl = lane & 31, hi = lane >> 5;
  const int row0 = blockIdx.x * 32;
  const int n = row0 >> 12;
  const int nb = row0 >> 10;
  const int trow = (row0 & 1023) + cl;
  const int MLS = 24 * 2 * TT;

  // combine weights per head
  float wsp[2][NSPLIT];
#pragma unroll
  for (int h = 0; h < 2; ++h) {
    int mi = (nb * 2 + h) * TT + trow;
    float mv[NSPLIT], lv[NSPLIT];
#pragma unroll
    for (int sp = 0; sp < NSPLIT; ++sp) { mv[sp] = Mp[mi + sp * MLS]; lv[sp] = Lp[mi + sp * MLS]; }
    float ms = mv[0];
#pragma unroll
    for (int sp = 1; sp < NSPLIT; ++sp) ms = fmaxf(ms, mv[sp]);
    float den = 0.f;
#pragma unroll
    for (int sp = 0; sp < NSPLIT; ++sp) { wsp[h][sp] = exp2f(mv[sp] - ms); den = fmaf(lv[sp], wsp[h][sp], den); }
    float inv = 1.0f / den;
#pragma unroll
    for (int sp = 0; sp < NSPLIT; ++sp) wsp[h][sp] *= inv;
  }

  // A-frags: combine partials
  u32x4 af[4];
#pragma unroll
  for (int ks = 0; ks < 4; ++ks) {
    int h = ks >> 1;
    size_t off = (size_t)(row0 + cl) * 64 + ks * 16 + hi * 8;
    f32x2 s0 = {}, s1 = {}, s2 = {}, s3 = {};
#pragma unroll
    for (int sp = 0; sp < NSPLIT; ++sp) {
      u32x4 v = *(const u32x4*)(Op + (size_t)sp * NROW * 64 + off);
      float wv = wsp[h][sp];
      s0 += f32x2{b2f(v[0] & 0xffffu), b2f(v[0] >> 16)} * wv;
      s1 += f32x2{b2f(v[1] & 0xffffu), b2f(v[1] >> 16)} * wv;
      s2 += f32x2{b2f(v[2] & 0xffffu), b2f(v[2] >> 16)} * wv;
      s3 += f32x2{b2f(v[3] & 0xffffu), b2f(v[3] >> 16)} * wv;
    }
    af[ks] = u32x4{pkbf(s0.x, s0.y), pkbf(s1.x, s1.y), pkbf(s2.x, s2.y), pkbf(s3.x, s3.y)};
  }

  const __hip_bfloat16* Bp = Bo + ((size_t)n * 768 + w * 192 + cl) * 64 + hi * 8;
  f32x16 acc[6] = {};
#pragma unroll
  for (int ks = 0; ks < 4; ++ks) {
#pragma unroll
    for (int t = 0; t < 6; ++t) {
      u32x4 bb = *(const u32x4*)(Bp + (size_t)(t * 32) * 64 + ks * 16);
      acc[t] = mfma32(af[ks], bb, acc[t]);
    }
  }

  float s1[16], s2[16];
#pragma unroll
  for (int r = 0; r < 16; ++r) { s1[r] = 0.f; s2[r] = 0.f; }
#pragma unroll
  for (int t = 0; t < 6; ++t) {
#pragma unroll
    for (int r = 0; r < 16; ++r) {
      int R = (r & 3) + 8 * (r >> 2) + 4 * hi;
      int col = w * 192 + t * 32 + cl;
      float y = acc[t][r] + x[(size_t)(row0 + R) * 768 + col];
      acc[t][r] = y;
      s1[r] += y;
      s2[r] = fmaf(y, y, s2[r]);
    }
  }
#pragma unroll
  for (int r = 0; r < 16; ++r) {
#pragma unroll
    for (int off = 1; off < 32; off <<= 1) {
      s1[r] += __shfl_xor(s1[r], off);
      s2[r] += __shfl_xor(s2[r], off);
    }
  }
  if (cl == 0) {
#pragma unroll
    for (int r = 0; r < 16; ++r) {
      int R = (r & 3) + 8 * (r >> 2) + 4 * hi;
      red[w][R][0] = s1[r];
      red[w][R][1] = s2[r];
    }
  }
  __syncthreads();
  if (tid < 64) {
    int R = tid & 31, st = tid >> 5;
    redf[R][st] = red[0][R][st] + red[1][R][st] + red[2][R][st] + red[3][R][st];
  }
  __syncthreads();

  float gv[6], bv[6];
#pragma unroll
  for (int t = 0; t < 6; ++t) {
    int col = w * 192 + t * 32 + cl;
    gv[t] = gamma[n * 768 + col];
    bv[t] = beta[n * 768 + col];
  }
#pragma unroll
  for (int r = 0; r < 16; ++r) {
    int R = (r & 3) + 8 * (r >> 2) + 4 * hi;
    float mu = redf[R][0] * (1.0f / 768.0f);
    float var = redf[R][1] * (1.0f / 768.0f) - mu * mu;
    float rs = rsqrtf(var + LNEPS);
#pragma unroll
    for (int t = 0; t < 6; ++t) {
      int col = w * 192 + t * 32 + cl;
      out[(size_t)(row0 + R) * 768 + col] = (acc[t][r] - mu) * rs * gv[t] + bv[t];
    }
  }
}

// ---------------------------------------------------------------------------
extern "C" void kernel_launch(void* const* d_in, const int* in_sizes, int n_in,
                              void* d_out, int out_size, void* d_ws, size_t ws_size,
                              hipStream_t stream) {
  const float* x     = (const float*)d_in[0];
  const float* hist  = (const float*)d_in[1];
  const int*   mask  = (const int*)d_in[2];
  const float* Wq    = (const float*)d_in[3];
  const float* Wk    = (const float*)d_in[4];
  const float* Wv    = (const float*)d_in[5];
  const float* Wo    = (const float*)d_in[6];
  const float* gamma = (const float*)d_in[7];
  const float* beta  = (const float*)d_in[8];
  float* out = (float*)d_out;

  char* ws = (char*)d_ws;
  __hip_bfloat16* Qb  = (__hip_bfloat16*)ws;  ws += (size_t)NROW * II * 2;
  __hip_bfloat16* Kh  = (__hip_bfloat16*)ws;  ws += (size_t)NKVROW * II * 2;
  __hip_bfloat16* Vt2 = (__hip_bfloat16*)ws;  ws += (size_t)NKVROW * II * 2;
  __hip_bfloat16* Op  = (__hip_bfloat16*)ws;  ws += (size_t)NSPLIT * NROW * II * 2;
  float* Mp           = (float*)ws;           ws += (size_t)NSPLIT * 24 * 2 * TT * 4;
  float* Lp           = (float*)ws;           ws += (size_t)NSPLIT * 24 * 2 * TT * 4;
  __hip_bfloat16* Bkv = (__hip_bfloat16*)ws;  ws += (size_t)128 * 768 * 2;
  __hip_bfloat16* Bq  = (__hip_bfloat16*)ws;  ws += (size_t)NDOM * 64 * 768 * 2;
  __hip_bfloat16* Bo  = (__hip_bfloat16*)ws;  ws += (size_t)NDOM * 768 * 64 * 2;
  float* bias2        = (float*)ws;           ws += (size_t)BB * SS * 4;

  const int PREP_N = 128*768 + NDOM*64*768 + NDOM*768*64 + BB*SS;
  prep_kernel<<<(PREP_N + 255) / 256, 256, 0, stream>>>(mask, Wk, Wv, Wq, Wo, Bkv, Bq, Bo, bias2);
  qkv_gemm_kernel<<<NKVB + NQB, 256, 0, stream>>>(x, hist, Bkv, Bq, Qb, Kh, Vt2);
  attn_kernel<<<48 * 8 * NSPLIT, 256, 0, stream>>>(Qb, Kh, Vt2, bias2, Op, Mp, Lp);
  oproj_ln_kernel<<<NROW / 32, 256, 0, stream>>>(x, Op, Mp, Lp, Bo, gamma, beta, out);
}

// Round 10
// 206.900 us; speedup vs baseline: 1.5067x; 1.0594x over previous
//
#include <hip/hip_runtime.h>
#include <hip/hip_bf16.h>
#include <math.h>

#define NDOM 6
#define BB 4
#define TT 1024
#define DD 768
#define PP 3
#define HH 2
#define DHH 32
#define II 64
#define SS (PP*TT)        // 3072
#define NROW (NDOM*BB*TT) // 24576
#define NKVROW (NDOM*BB*SS)
#define NSPLIT 4
#define NKVB (NKVROW/32)  // 2304
#define NQB  (NROW/32)    // 768
#define LNEPS 1e-5f

typedef unsigned int uint;
typedef uint  u32x4  __attribute__((ext_vector_type(4)));
typedef int   i32x2  __attribute__((ext_vector_type(2)));
typedef float f32x2  __attribute__((ext_vector_type(2)));
typedef float f32x4  __attribute__((ext_vector_type(4)));
typedef float f32x16 __attribute__((ext_vector_type(16)));
typedef __bf16 bf16x8 __attribute__((ext_vector_type(8)));

// D = A(32x16) * B(16x32) + C.  A row = lane&31, k = (lane>>5)*8+j.
// B col = lane&31, k = (lane>>5)*8+j.  D: col = lane&31, row=(r&3)+8*(r>>2)+4*(lane>>5).
__device__ __forceinline__ f32x16 mfma32(u32x4 a, u32x4 b, f32x16 c) {
  return __builtin_amdgcn_mfma_f32_32x32x16_bf16(
      __builtin_bit_cast(bf16x8, a), __builtin_bit_cast(bf16x8, b), c, 0, 0, 0);
}

__device__ __forceinline__ uint pkbf(float a, float b) {
  union { __bf16 h[2]; uint u; } v;
  v.h[0] = (__bf16)a; v.h[1] = (__bf16)b;
  return v.u;
}
__device__ __forceinline__ float b2f(uint u16) {
  union { uint i; float f; } v; v.i = u16 << 16; return v.f;
}

// x gets {a_lo | partner's b}, y gets {partner's a | b}  (32-lane halves)
__device__ __forceinline__ void plswap(uint a, uint b, uint& x, uint& y) {
#if __has_builtin(__builtin_amdgcn_permlane32_swap)
  i32x2 r = __builtin_amdgcn_permlane32_swap((int)a, (int)b, false, false);
  x = (uint)r.x; y = (uint)r.y;
#else
  uint sa = __shfl_xor(a, 32), sb = __shfl_xor(b, 32);
  bool h1 = (threadIdx.x & 32) != 0;
  x = h1 ? sb : a;
  y = h1 ? b : sa;
#endif
}

// ---------------------------------------------------------------------------
// Prep: fragment-major bf16 weights + exp2-domain mask bias.
// Bkvf[slot][c][8]: slot=ks*2+hi (96), c: 0-63 Wk col, 64-127 Wv col.
// Bqf[n][slot][c][8]: 64 cols per n.
// Bo[n][d][i] = Wo[n][i][d] (row-major, oproj unchanged).
// bias2[b][s] = (1-mask[b][s%T]) * (-10000) * log2(e)
// ---------------------------------------------------------------------------
__global__ __launch_bounds__(256) void prep_kernel(
    const int* __restrict__ mask, const float* __restrict__ Wk,
    const float* __restrict__ Wv, const float* __restrict__ Wq,
    const float* __restrict__ Wo,
    __hip_bfloat16* __restrict__ Bkvf, __hip_bfloat16* __restrict__ Bqf,
    __hip_bfloat16* __restrict__ Bo, float* __restrict__ bias2)
{
  int i = blockIdx.x * 256 + threadIdx.x;
  const int N1 = 96 * 128 * 8;       // Bkvf
  const int N2 = NDOM * 96 * 64 * 8; // Bqf
  const int N3 = NDOM * 768 * 64;    // Bo
  if (i < N1) {
    int e = i & 7, c = (i >> 3) & 127, slot = i >> 10;
    int k = (slot >> 1) * 16 + (slot & 1) * 8 + e;
    float v = (c < 64) ? Wk[k * 64 + c] : Wv[k * 64 + (c - 64)];
    Bkvf[i] = __float2bfloat16(v);
  } else if (i < N1 + N2) {
    int j = i - N1;
    int n = j / 49152, rem = j % 49152;
    int e = rem & 7, c = (rem >> 3) & 63, slot = rem >> 9;
    int k = (slot >> 1) * 16 + (slot & 1) * 8 + e;
    Bqf[j] = __float2bfloat16(Wq[((size_t)n * 768 + k) * 64 + c]);
  } else if (i < N1 + N2 + N3) {
    int j = i - N1 - N2;
    int n = j / (768 * 64);
    int rem = j % (768 * 64);
    int d = rem / 64, k = rem % 64;
    Bo[j] = __float2bfloat16(Wo[((size_t)n * 64 + k) * 768 + d]);
  } else if (i < N1 + N2 + N3 + BB * SS) {
    int j = i - N1 - N2 - N3;
    int b = j / SS, s = j % SS;
    bias2[j] = (1.0f - (float)mask[b * TT + (s & (TT - 1))]) * (-14426.950408889634f);
  }
}

// ---------------------------------------------------------------------------
// Fused Q + KV projection GEMM, BM=32, BK=768 (SINGLE PASS over hist/x:
// each block streams one contiguous 96 KB region once -> DRAM-friendly).
// 48 KB XOR-swizzled bf16 LDS; B loads are contiguous fragment-major.
// Blocks [0,2304): history rows -> Kh + Vt2.  [2304,3072): x rows -> Q.
// KV: wave w in {Kh0,Kh1,Vh0,Vh1}.  Q: waves 0/1 = col halves (2/3 stage only).
// ---------------------------------------------------------------------------
__global__ __launch_bounds__(256) void qkv_gemm_kernel(
    const float* __restrict__ x, const float* __restrict__ hist,
    const __hip_bfloat16* __restrict__ Bkvf, const __hip_bfloat16* __restrict__ Bqf,
    __hip_bfloat16* __restrict__ Qo, __hip_bfloat16* __restrict__ Kh,
    __hip_bfloat16* __restrict__ Vt2)
{
  __shared__ uint As[12288];   // [32 rows][96 slots][4 u32], slot^row swizzle
  const int tid = threadIdx.x;
  const int lane = tid & 63, w = tid >> 6;
  const int cl = lane & 31, hi = lane >> 5;
  const int row = tid >> 3, oct = tid & 7;

  const bool isKV = blockIdx.x < NKVB;
  const float* Asrc;
  int nb = 0, s0 = 0, n = 0, brow = 0;
  if (isKV) {
    brow = blockIdx.x * 32;
    nb = brow / SS; n = nb >> 2;
    int b = nb & 3;
    s0 = brow % SS;
    int p = s0 / TT, t0 = s0 % TT;          // 32 | 1024: block stays in one p
    Asrc = hist + (((size_t)(p * NDOM + n) * BB + b) * TT + t0) * 768;
  } else {
    brow = (blockIdx.x - NKVB) * 32;
    n = brow >> 12;
    Asrc = x + (size_t)brow * 768;
  }

  // stage: 32 rows x 768 f32 -> bf16 LDS, each row read once, stream order
  {
    const float* src = Asrc + (size_t)row * 768;
    f32x4 fb[12];
#pragma unroll
    for (int half = 0; half < 2; ++half) {
#pragma unroll
      for (int j = 0; j < 6; ++j) {
        int s = oct + 8 * (half * 6 + j);
        fb[2 * j]     = *(const f32x4*)(src + s * 8);
        fb[2 * j + 1] = *(const f32x4*)(src + s * 8 + 4);
      }
#pragma unroll
      for (int j = 0; j < 6; ++j) {
        int s = oct + 8 * (half * 6 + j);
        int sw = (s & ~15) | ((s & 15) ^ (row & 15));
        *(u32x4*)&As[row * 384 + sw * 4] =
            u32x4{pkbf(fb[2*j].x, fb[2*j].y), pkbf(fb[2*j].z, fb[2*j].w),
                  pkbf(fb[2*j+1].x, fb[2*j+1].y), pkbf(fb[2*j+1].z, fb[2*j+1].w)};
      }
    }
  }
  __syncthreads();

  if (isKV) {
    const __hip_bfloat16* bb = Bkvf + (size_t)(w * 32 + cl) * 8;
    f32x16 aE = {}, aO = {};
#pragma unroll 4
    for (int ks = 0; ks < 48; ++ks) {
      int slot = ks * 2 + hi;
      int sw = (slot & ~15) | ((slot & 15) ^ (cl & 15));
      u32x4 a = *(const u32x4*)&As[cl * 384 + sw * 4];
      u32x4 b = *(const u32x4*)(bb + (size_t)slot * 128 * 8);
      if (ks & 1) aO = mfma32(a, b, aO); else aE = mfma32(a, b, aE);
    }
    f32x16 acc = aE + aO;
    if (w < 2) {        // K head w: Kh[(nb*2+w)*SS + s][32]
      size_t base = (size_t)(nb * 2 + w) * SS;
#pragma unroll
      for (int r = 0; r < 16; ++r) {
        int rl = (r & 3) + 8 * (r >> 2) + 4 * hi;
        Kh[(base + s0 + rl) * 32 + cl] = __float2bfloat16(acc[r]);
      }
    } else {            // V head w-2 -> Vt2[nb][h][sb][c][8]
      int h = w - 2;
#pragma unroll
      for (int k = 0; k < 4; ++k) {
        int sb = (s0 + 8 * k) >> 3;
        size_t A0 = (((size_t)(nb * 2 + h) * (SS / 8) + sb) * 32 + cl) * 8 + 4 * hi;
        *(uint2*)(Vt2 + A0) = uint2{pkbf(acc[4*k], acc[4*k+1]), pkbf(acc[4*k+2], acc[4*k+3])};
      }
    }
  } else if (w < 2) {
    const __hip_bfloat16* bb = Bqf + (size_t)n * 49152 + (size_t)(w * 32 + cl) * 8;
    f32x16 aE = {}, aO = {};
#pragma unroll 4
    for (int ks = 0; ks < 48; ++ks) {
      int slot = ks * 2 + hi;
      int sw = (slot & ~15) | ((slot & 15) ^ (cl & 15));
      u32x4 a = *(const u32x4*)&As[cl * 384 + sw * 4];
      u32x4 b = *(const u32x4*)(bb + (size_t)slot * 64 * 8);
      if (ks & 1) aO = mfma32(a, b, aO); else aE = mfma32(a, b, aE);
    }
    f32x16 acc = aE + aO;
#pragma unroll
    for (int r = 0; r < 16; ++r) {
      int rl = (r & 3) + 8 * (r >> 2) + 4 * hi;
      Qo[(size_t)(brow + rl) * 64 + w * 32 + cl] = __float2bfloat16(acc[r]);
    }
  }
}

// ---------------------------------------------------------------------------
// Flash attention, split-S by 4.  Block = 4 waves sharing one (n,b,h,split):
// wave w owns q-tile tq*4+w; all waves stream the SAME K/V tiles in lockstep
// (raw s_barrier per iter, no LDS) -> L1 broadcast hits.
// ---------------------------------------------------------------------------
struct KV { u32x4 k0, k1, k2, k3, v0, v1, v2, v3; };

__global__ __launch_bounds__(256) void attn_kernel(
    const __hip_bfloat16* __restrict__ Q, const __hip_bfloat16* __restrict__ Kh,
    const __hip_bfloat16* __restrict__ Vt2, const float* __restrict__ bias2,
    __hip_bfloat16* __restrict__ Op, float* __restrict__ Mp, float* __restrict__ Lp)
{
  const int tid = threadIdx.x;
  const int lane = tid & 63, w = tid >> 6;
  const int cl = lane & 31, hi = lane >> 5;
  const int bid = blockIdx.x;
  const int g = bid % 48;            // (n,b,h) group -> fixed XCD (48 % 8 == 0)
  const int rest = bid / 48;         // 0..31
  const int sp = rest >> 3;          // split 0..3
  const int tq = rest & 7;           // q super-tile 0..7
  const int qtile = tq * 4 + w;      // 0..31
  const int h = g & 1, nb = g >> 1;
  const int b = nb & 3;
  const int qrow = nb * TT + qtile * 32;
  const int sbase = sp * (SS / NSPLIT);   // 768 keys per split

  const __hip_bfloat16* Qp = Q + (size_t)(qrow + cl) * 64 + h * 32 + hi * 8;
  u32x4 qf0 = *(const u32x4*)Qp;
  u32x4 qf1 = *(const u32x4*)(Qp + 16);

  const __hip_bfloat16* Kp = Kh + ((size_t)(nb * 2 + h) * SS + sbase) * 32;
  const __hip_bfloat16* Vp = Vt2 + (size_t)(nb * 2 + h) * SS * 32 + (size_t)sbase * 32;
  const float* Bp = bias2 + b * SS + sbase + hi * 4;

  const float scale2 = 0.17677669529663687f * 1.4426950408889634f;
  const f32x2 sc2 = {scale2, scale2};

  f32x16 ot = {};
  float m = -1e30f, lsum = 0.f;

  auto loadKV = [&](int it) {
    KV t;
    const __hip_bfloat16* kp = Kp + (size_t)it * 64 * 32;
    t.k0 = *(const u32x4*)(kp + cl * 32 + hi * 8);
    t.k1 = *(const u32x4*)(kp + cl * 32 + 16 + hi * 8);
    t.k2 = *(const u32x4*)(kp + 1024 + cl * 32 + hi * 8);
    t.k3 = *(const u32x4*)(kp + 1024 + cl * 32 + 16 + hi * 8);
    const __hip_bfloat16* vp = Vp + (size_t)it * 64 * 32;
    t.v0 = *(const u32x4*)(vp + ((0 * 2 + hi) * 32 + cl) * 8);
    t.v1 = *(const u32x4*)(vp + ((1 * 2 + hi) * 32 + cl) * 8);
    t.v2 = *(const u32x4*)(vp + ((2 * 2 + hi) * 32 + cl) * 8);
    t.v3 = *(const u32x4*)(vp + ((3 * 2 + hi) * 32 + cl) * 8);
    return t;
  };

  auto compute = [&](const KV& t, int it) {
    f32x16 pz0 = {}, pz1 = {};
    pz0 = mfma32(t.k0, qf0, pz0);
    pz0 = mfma32(t.k1, qf1, pz0);
    pz1 = mfma32(t.k2, qf0, pz1);
    pz1 = mfma32(t.k3, qf1, pz1);
    const float* bp = Bp + it * 64;
    f32x4 b4[8];
#pragma unroll
    for (int q = 0; q < 8; ++q) b4[q] = *(const f32x4*)(bp + 8 * q);
    f32x2 p2[16];
#pragma unroll
    for (int i = 0; i < 8; ++i) {
      f32x4 bq0 = b4[i >> 1];
      f32x4 bq1 = b4[4 + (i >> 1)];
      f32x2 bv0 = (i & 1) ? f32x2{bq0.z, bq0.w} : f32x2{bq0.x, bq0.y};
      f32x2 bv1 = (i & 1) ? f32x2{bq1.z, bq1.w} : f32x2{bq1.x, bq1.y};
      p2[i]     = f32x2{pz0[2*i], pz0[2*i+1]} * sc2 + bv0;
      p2[8 + i] = f32x2{pz1[2*i], pz1[2*i+1]} * sc2 + bv1;
    }
    f32x2 mx = p2[0];
#pragma unroll
    for (int i = 1; i < 16; ++i) {
      mx.x = fmaxf(mx.x, p2[i].x);
      mx.y = fmaxf(mx.y, p2[i].y);
    }
    float tm = fmaxf(mx.x, mx.y);
    tm = fmaxf(tm, __shfl_xor(tm, 32));
    if (!__all(tm - m <= 8.f)) {       // defer-max
      float mn = fmaxf(m, tm);
      float f = exp2f(m - mn);
#pragma unroll
      for (int i = 0; i < 16; ++i) ot[i] *= f;
      lsum *= f;
      m = mn;
    }
    const f32x2 m2 = {m, m};
    f32x2 s2 = {0.f, 0.f};
#pragma unroll
    for (int i = 0; i < 16; ++i) {
      f32x2 d = p2[i] - m2;
      f32x2 e = {exp2f(d.x), exp2f(d.y)};
      p2[i] = e;
      s2 += e;
    }
    float ts = s2.x + s2.y;
    ts += __shfl_xor(ts, 32);
    lsum += ts;
    // P -> bf16 B-frags via permlane32_swap
    uint cv[16];
#pragma unroll
    for (int i = 0; i < 16; ++i) cv[i] = pkbf(p2[i].x, p2[i].y);
    u32x4 pf0, pf1, pf2, pf3;
    {
      uint x0, y0, x1, y1;
      plswap(cv[0], cv[2],  x0, y0); plswap(cv[1], cv[3],  x1, y1);
      pf0 = u32x4{x0, x1, y0, y1};
      plswap(cv[4], cv[6],  x0, y0); plswap(cv[5], cv[7],  x1, y1);
      pf1 = u32x4{x0, x1, y0, y1};
      plswap(cv[8], cv[10], x0, y0); plswap(cv[9], cv[11], x1, y1);
      pf2 = u32x4{x0, x1, y0, y1};
      plswap(cv[12], cv[14], x0, y0); plswap(cv[13], cv[15], x1, y1);
      pf3 = u32x4{x0, x1, y0, y1};
    }
    ot = mfma32(t.v0, pf0, ot);
    ot = mfma32(t.v1, pf1, ot);
    ot = mfma32(t.v2, pf2, ot);
    ot = mfma32(t.v3, pf3, ot);
  };

  KV cur = loadKV(0);
#pragma unroll 1
  for (int it = 0; it < 12; ++it) {
    KV nxt = loadKV(it + 1 < 12 ? it + 1 : 11);
    compute(cur, it);
    cur = nxt;
    __builtin_amdgcn_s_barrier();   // keep the 4 waves' K/V streams in lockstep (L1 reuse)
  }

  // store unnormalized O^T partial (bf16) + m/l
  __hip_bfloat16* op = Op + ((size_t)sp * NROW + qrow + cl) * 64 + h * 32 + 4 * hi;
#pragma unroll
  for (int k = 0; k < 4; ++k) {
    uint2 wv = {pkbf(ot[4*k], ot[4*k+1]), pkbf(ot[4*k+2], ot[4*k+3])};
    *(uint2*)(op + 8 * k) = wv;
  }
  if (lane < 32) {
    int mi = ((sp * 24 + nb) * 2 + h) * TT + qtile * 32 + cl;
    Mp[mi] = m;
    Lp[mi] = lsum;
  }
}

// ---------------------------------------------------------------------------
// Fused split-combine + out-projection (MFMA) + residual + LayerNorm.
// Block 256 = 4 waves, 32 rows; wave w owns cols [w*192, +192).
// ---------------------------------------------------------------------------
__global__ __launch_bounds__(256) void oproj_ln_kernel(
    const float* __restrict__ x, const __hip_bfloat16* __restrict__ Op,
    const float* __restrict__ Mp, const float* __restrict__ Lp,
    const __hip_bfloat16* __restrict__ Bo, const float* __restrict__ gamma,
    const float* __restrict__ beta, float* __restrict__ out)
{
  __shared__ float red[4][32][2];
  __shared__ float redf[32][2];
  const int tid = threadIdx.x;
  const int lane = tid & 63, w = tid >> 6;
  const int cl = lane & 31, hi = lane >> 5;
  const int row0 = blockIdx.x * 32;
  const int n = row0 >> 12;
  const int nb = row0 >> 10;
  const int trow = (row0 & 1023) + cl;
  const int MLS = 24 * 2 * TT;

  // combine weights per head
  float wsp[2][NSPLIT];
#pragma unroll
  for (int h = 0; h < 2; ++h) {
    int mi = (nb * 2 + h) * TT + trow;
    float mv[NSPLIT], lv[NSPLIT];
#pragma unroll
    for (int sp = 0; sp < NSPLIT; ++sp) { mv[sp] = Mp[mi + sp * MLS]; lv[sp] = Lp[mi + sp * MLS]; }
    float ms = mv[0];
#pragma unroll
    for (int sp = 1; sp < NSPLIT; ++sp) ms = fmaxf(ms, mv[sp]);
    float den = 0.f;
#pragma unroll
    for (int sp = 0; sp < NSPLIT; ++sp) { wsp[h][sp] = exp2f(mv[sp] - ms); den = fmaf(lv[sp], wsp[h][sp], den); }
    float inv = 1.0f / den;
#pragma unroll
    for (int sp = 0; sp < NSPLIT; ++sp) wsp[h][sp] *= inv;
  }

  // A-frags: combine partials
  u32x4 af[4];
#pragma unroll
  for (int ks = 0; ks < 4; ++ks) {
    int h = ks >> 1;
    size_t off = (size_t)(row0 + cl) * 64 + ks * 16 + hi * 8;
    f32x2 s0 = {}, s1 = {}, s2 = {}, s3 = {};
#pragma unroll
    for (int sp = 0; sp < NSPLIT; ++sp) {
      u32x4 v = *(const u32x4*)(Op + (size_t)sp * NROW * 64 + off);
      float wv = wsp[h][sp];
      s0 += f32x2{b2f(v[0] & 0xffffu), b2f(v[0] >> 16)} * wv;
      s1 += f32x2{b2f(v[1] & 0xffffu), b2f(v[1] >> 16)} * wv;
      s2 += f32x2{b2f(v[2] & 0xffffu), b2f(v[2] >> 16)} * wv;
      s3 += f32x2{b2f(v[3] & 0xffffu), b2f(v[3] >> 16)} * wv;
    }
    af[ks] = u32x4{pkbf(s0.x, s0.y), pkbf(s1.x, s1.y), pkbf(s2.x, s2.y), pkbf(s3.x, s3.y)};
  }

  const __hip_bfloat16* Bp = Bo + ((size_t)n * 768 + w * 192 + cl) * 64 + hi * 8;
  f32x16 acc[6] = {};
#pragma unroll
  for (int ks = 0; ks < 4; ++ks) {
#pragma unroll
    for (int t = 0; t < 6; ++t) {
      u32x4 bb = *(const u32x4*)(Bp + (size_t)(t * 32) * 64 + ks * 16);
      acc[t] = mfma32(af[ks], bb, acc[t]);
    }
  }

  float s1[16], s2[16];
#pragma unroll
  for (int r = 0; r < 16; ++r) { s1[r] = 0.f; s2[r] = 0.f; }
#pragma unroll
  for (int t = 0; t < 6; ++t) {
#pragma unroll
    for (int r = 0; r < 16; ++r) {
      int R = (r & 3) + 8 * (r >> 2) + 4 * hi;
      int col = w * 192 + t * 32 + cl;
      float y = acc[t][r] + x[(size_t)(row0 + R) * 768 + col];
      acc[t][r] = y;
      s1[r] += y;
      s2[r] = fmaf(y, y, s2[r]);
    }
  }
#pragma unroll
  for (int r = 0; r < 16; ++r) {
#pragma unroll
    for (int off = 1; off < 32; off <<= 1) {
      s1[r] += __shfl_xor(s1[r], off);
      s2[r] += __shfl_xor(s2[r], off);
    }
  }
  if (cl == 0) {
#pragma unroll
    for (int r = 0; r < 16; ++r) {
      int R = (r & 3) + 8 * (r >> 2) + 4 * hi;
      red[w][R][0] = s1[r];
      red[w][R][1] = s2[r];
    }
  }
  __syncthreads();
  if (tid < 64) {
    int R = tid & 31, st = tid >> 5;
    redf[R][st] = red[0][R][st] + red[1][R][st] + red[2][R][st] + red[3][R][st];
  }
  __syncthreads();

  float gv[6], bv[6];
#pragma unroll
  for (int t = 0; t < 6; ++t) {
    int col = w * 192 + t * 32 + cl;
    gv[t] = gamma[n * 768 + col];
    bv[t] = beta[n * 768 + col];
  }
#pragma unroll
  for (int r = 0; r < 16; ++r) {
    int R = (r & 3) + 8 * (r >> 2) + 4 * hi;
    float mu = redf[R][0] * (1.0f / 768.0f);
    float var = redf[R][1] * (1.0f / 768.0f) - mu * mu;
    float rs = rsqrtf(var + LNEPS);
#pragma unroll
    for (int t = 0; t < 6; ++t) {
      int col = w * 192 + t * 32 + cl;
      out[(size_t)(row0 + R) * 768 + col] = (acc[t][r] - mu) * rs * gv[t] + bv[t];
    }
  }
}

// ---------------------------------------------------------------------------
extern "C" void kernel_launch(void* const* d_in, const int* in_sizes, int n_in,
                              void* d_out, int out_size, void* d_ws, size_t ws_size,
                              hipStream_t stream) {
  const float* x     = (const float*)d_in[0];
  const float* hist  = (const float*)d_in[1];
  const int*   mask  = (const int*)d_in[2];
  const float* Wq    = (const float*)d_in[3];
  const float* Wk    = (const float*)d_in[4];
  const float* Wv    = (const float*)d_in[5];
  const float* Wo    = (const float*)d_in[6];
  const float* gamma = (const float*)d_in[7];
  const float* beta  = (const float*)d_in[8];
  float* out = (float*)d_out;

  char* ws = (char*)d_ws;
  __hip_bfloat16* Qb  = (__hip_bfloat16*)ws;  ws += (size_t)NROW * II * 2;
  __hip_bfloat16* Kh  = (__hip_bfloat16*)ws;  ws += (size_t)NKVROW * II * 2;
  __hip_bfloat16* Vt2 = (__hip_bfloat16*)ws;  ws += (size_t)NKVROW * II * 2;
  __hip_bfloat16* Op  = (__hip_bfloat16*)ws;  ws += (size_t)NSPLIT * NROW * II * 2;
  float* Mp           = (float*)ws;           ws += (size_t)NSPLIT * 24 * 2 * TT * 4;
  float* Lp           = (float*)ws;           ws += (size_t)NSPLIT * 24 * 2 * TT * 4;
  __hip_bfloat16* Bkvf = (__hip_bfloat16*)ws; ws += (size_t)96 * 128 * 8 * 2;
  __hip_bfloat16* Bqf  = (__hip_bfloat16*)ws; ws += (size_t)NDOM * 96 * 64 * 8 * 2;
  __hip_bfloat16* Bo  = (__hip_bfloat16*)ws;  ws += (size_t)NDOM * 768 * 64 * 2;
  float* bias2        = (float*)ws;           ws += (size_t)BB * SS * 4;

  const int PREP_N = 96*128*8 + NDOM*96*64*8 + NDOM*768*64 + BB*SS;
  prep_kernel<<<(PREP_N + 255) / 256, 256, 0, stream>>>(mask, Wk, Wv, Wq, Wo, Bkvf, Bqf, Bo, bias2);
  qkv_gemm_kernel<<<NKVB + NQB, 256, 0, stream>>>(x, hist, Bkvf, Bqf, Qb, Kh, Vt2);
  attn_kernel<<<48 * 8 * NSPLIT, 256, 0, stream>>>(Qb, Kh, Vt2, bias2, Op, Mp, Lp);
  oproj_ln_kernel<<<NROW / 32, 256, 0, stream>>>(x, Op, Mp, Lp, Bo, gamma, beta, out);
}

// Round 11
// 202.677 us; speedup vs baseline: 1.5381x; 1.0208x over previous
//
#include <hip/hip_runtime.h>
#include <hip/hip_bf16.h>
#include <math.h>

#define NDOM 6
#define BB 4
#define TT 1024
#define DD 768
#define PP 3
#define HH 2
#define DHH 32
#define II 64
#define SS (PP*TT)        // 3072
#define NROW (NDOM*BB*TT) // 24576
#define NKVROW (NDOM*BB*SS)
#define NSPLIT 4
#define NKVB (NKVROW/32)  // 2304
#define NQB  (NROW/32)    // 768
#define LNEPS 1e-5f

typedef unsigned int uint;
typedef uint  u32x4  __attribute__((ext_vector_type(4)));
typedef int   i32x2  __attribute__((ext_vector_type(2)));
typedef float f32x2  __attribute__((ext_vector_type(2)));
typedef float f32x4  __attribute__((ext_vector_type(4)));
typedef float f32x16 __attribute__((ext_vector_type(16)));
typedef __bf16 bf16x8 __attribute__((ext_vector_type(8)));

// D = A(32x16) * B(16x32) + C.  A row = lane&31, k = (lane>>5)*8+j.
// B col = lane&31, k = (lane>>5)*8+j.  D: col = lane&31, row=(r&3)+8*(r>>2)+4*(lane>>5).
__device__ __forceinline__ f32x16 mfma32(u32x4 a, u32x4 b, f32x16 c) {
  return __builtin_amdgcn_mfma_f32_32x32x16_bf16(
      __builtin_bit_cast(bf16x8, a), __builtin_bit_cast(bf16x8, b), c, 0, 0, 0);
}

__device__ __forceinline__ uint pkbf(float a, float b) {
  union { __bf16 h[2]; uint u; } v;
  v.h[0] = (__bf16)a; v.h[1] = (__bf16)b;
  return v.u;
}
__device__ __forceinline__ float b2f(uint u16) {
  union { uint i; float f; } v; v.i = u16 << 16; return v.f;
}

// x gets {a_lo | partner's b}, y gets {partner's a | b}  (32-lane halves)
__device__ __forceinline__ void plswap(uint a, uint b, uint& x, uint& y) {
#if __has_builtin(__builtin_amdgcn_permlane32_swap)
  i32x2 r = __builtin_amdgcn_permlane32_swap((int)a, (int)b, false, false);
  x = (uint)r.x; y = (uint)r.y;
#else
  uint sa = __shfl_xor(a, 32), sb = __shfl_xor(b, 32);
  bool h1 = (threadIdx.x & 32) != 0;
  x = h1 ? sb : a;
  y = h1 ? b : sa;
#endif
}

// ---------------------------------------------------------------------------
// Prep: fragment-major bf16 weights + exp2-domain mask bias.
// Bkvf[slot][c][8]: slot=ks*2+hi (96), c: 0-63 Wk col, 64-127 Wv col.
// Bqf[n][slot][c][8]: 64 cols per n.
// Bo[n][d][i] = Wo[n][i][d] (row-major, oproj unchanged).
// bias2[b][s] = (1-mask[b][s%T]) * (-10000) * log2(e)
// ---------------------------------------------------------------------------
__global__ __launch_bounds__(256) void prep_kernel(
    const int* __restrict__ mask, const float* __restrict__ Wk,
    const float* __restrict__ Wv, const float* __restrict__ Wq,
    const float* __restrict__ Wo,
    __hip_bfloat16* __restrict__ Bkvf, __hip_bfloat16* __restrict__ Bqf,
    __hip_bfloat16* __restrict__ Bo, float* __restrict__ bias2)
{
  int i = blockIdx.x * 256 + threadIdx.x;
  const int N1 = 96 * 128 * 8;       // Bkvf
  const int N2 = NDOM * 96 * 64 * 8; // Bqf
  const int N3 = NDOM * 768 * 64;    // Bo
  if (i < N1) {
    int e = i & 7, c = (i >> 3) & 127, slot = i >> 10;
    int k = (slot >> 1) * 16 + (slot & 1) * 8 + e;
    float v = (c < 64) ? Wk[k * 64 + c] : Wv[k * 64 + (c - 64)];
    Bkvf[i] = __float2bfloat16(v);
  } else if (i < N1 + N2) {
    int j = i - N1;
    int n = j / 49152, rem = j % 49152;
    int e = rem & 7, c = (rem >> 3) & 63, slot = rem >> 9;
    int k = (slot >> 1) * 16 + (slot & 1) * 8 + e;
    Bqf[j] = __float2bfloat16(Wq[((size_t)n * 768 + k) * 64 + c]);
  } else if (i < N1 + N2 + N3) {
    int j = i - N1 - N2;
    int n = j / (768 * 64);
    int rem = j % (768 * 64);
    int d = rem / 64, k = rem % 64;
    Bo[j] = __float2bfloat16(Wo[((size_t)n * 64 + k) * 768 + d]);
  } else if (i < N1 + N2 + N3 + BB * SS) {
    int j = i - N1 - N2 - N3;
    int b = j / SS, s = j % SS;
    bias2[j] = (1.0f - (float)mask[b * TT + (s & (TT - 1))]) * (-14426.950408889634f);
  }
}

// ---------------------------------------------------------------------------
// Fused Q + KV projection GEMM, BM=32, BK=768, flat-coalesced single-pass
// staging: per step, the 256 threads load 8 KB CONTIGUOUS (each wave 2 KB),
// LDS destination decoded from the flat offset.  6-step load batches keep
// 12 KB/wave in flight.  48 KB XOR-swizzled bf16 LDS; fragment-major B.
// Blocks [0,2304): history rows -> Kh + Vt2.  [2304,3072): x rows -> Q.
// ---------------------------------------------------------------------------
__global__ __launch_bounds__(256, 3) void qkv_gemm_kernel(
    const float* __restrict__ x, const float* __restrict__ hist,
    const __hip_bfloat16* __restrict__ Bkvf, const __hip_bfloat16* __restrict__ Bqf,
    __hip_bfloat16* __restrict__ Qo, __hip_bfloat16* __restrict__ Kh,
    __hip_bfloat16* __restrict__ Vt2)
{
  __shared__ uint As[12288];   // [32 rows][96 slots][4 u32], slot^row swizzle
  const int tid = threadIdx.x;
  const int lane = tid & 63, w = tid >> 6;
  const int cl = lane & 31, hi = lane >> 5;

  const bool isKV = blockIdx.x < NKVB;
  const float* Asrc;
  int nb = 0, s0 = 0, n = 0, brow = 0;
  if (isKV) {
    brow = blockIdx.x * 32;
    nb = brow / SS; n = nb >> 2;
    int b = nb & 3;
    s0 = brow % SS;
    int p = s0 / TT, t0 = s0 % TT;          // 32 | 1024: block stays in one p
    Asrc = hist + (((size_t)(p * NDOM + n) * BB + b) * TT + t0) * 768;
  } else {
    brow = (blockIdx.x - NKVB) * 32;
    n = brow >> 12;
    Asrc = x + (size_t)brow * 768;
  }

  // stage: 12 steps x 8KB contiguous; thread tid owns flat f32 [F, F+8)
  {
    f32x4 fb[12];
#pragma unroll
    for (int half = 0; half < 2; ++half) {
#pragma unroll
      for (int j = 0; j < 6; ++j) {
        int F = (half * 6 + j) * 2048 + tid * 8;
        fb[2 * j]     = *(const f32x4*)(Asrc + F);
        fb[2 * j + 1] = *(const f32x4*)(Asrc + F + 4);
      }
#pragma unroll
      for (int j = 0; j < 6; ++j) {
        int F = (half * 6 + j) * 2048 + tid * 8;
        int row = F / 768;
        int slot = (F - row * 768) >> 3;
        int sw = (slot & ~15) | ((slot & 15) ^ (row & 15));
        *(u32x4*)&As[row * 384 + sw * 4] =
            u32x4{pkbf(fb[2*j].x, fb[2*j].y), pkbf(fb[2*j].z, fb[2*j].w),
                  pkbf(fb[2*j+1].x, fb[2*j+1].y), pkbf(fb[2*j+1].z, fb[2*j+1].w)};
      }
    }
  }
  __syncthreads();

  if (isKV) {
    const __hip_bfloat16* bb = Bkvf + (size_t)(w * 32 + cl) * 8;
    f32x16 aE = {}, aO = {};
#pragma unroll 4
    for (int ks = 0; ks < 48; ++ks) {
      int slot = ks * 2 + hi;
      int sw = (slot & ~15) | ((slot & 15) ^ (cl & 15));
      u32x4 a = *(const u32x4*)&As[cl * 384 + sw * 4];
      u32x4 b = *(const u32x4*)(bb + (size_t)slot * 128 * 8);
      if (ks & 1) aO = mfma32(a, b, aO); else aE = mfma32(a, b, aE);
    }
    f32x16 acc = aE + aO;
    if (w < 2) {        // K head w: Kh[(nb*2+w)*SS + s][32]
      size_t base = (size_t)(nb * 2 + w) * SS;
#pragma unroll
      for (int r = 0; r < 16; ++r) {
        int rl = (r & 3) + 8 * (r >> 2) + 4 * hi;
        Kh[(base + s0 + rl) * 32 + cl] = __float2bfloat16(acc[r]);
      }
    } else {            // V head w-2 -> Vt2[nb][h][sb][c][8]
      int h = w - 2;
#pragma unroll
      for (int k = 0; k < 4; ++k) {
        int sb = (s0 + 8 * k) >> 3;
        size_t A0 = (((size_t)(nb * 2 + h) * (SS / 8) + sb) * 32 + cl) * 8 + 4 * hi;
        *(uint2*)(Vt2 + A0) = uint2{pkbf(acc[4*k], acc[4*k+1]), pkbf(acc[4*k+2], acc[4*k+3])};
      }
    }
  } else if (w < 2) {
    const __hip_bfloat16* bb = Bqf + (size_t)n * 49152 + (size_t)(w * 32 + cl) * 8;
    f32x16 aE = {}, aO = {};
#pragma unroll 4
    for (int ks = 0; ks < 48; ++ks) {
      int slot = ks * 2 + hi;
      int sw = (slot & ~15) | ((slot & 15) ^ (cl & 15));
      u32x4 a = *(const u32x4*)&As[cl * 384 + sw * 4];
      u32x4 b = *(const u32x4*)(bb + (size_t)slot * 64 * 8);
      if (ks & 1) aO = mfma32(a, b, aO); else aE = mfma32(a, b, aE);
    }
    f32x16 acc = aE + aO;
#pragma unroll
    for (int r = 0; r < 16; ++r) {
      int rl = (r & 3) + 8 * (r >> 2) + 4 * hi;
      Qo[(size_t)(brow + rl) * 64 + w * 32 + cl] = __float2bfloat16(acc[r]);
    }
  }
}

// ---------------------------------------------------------------------------
// Flash attention, split-S by 4.  Block = 4 waves sharing one (n,b,h,split):
// wave w owns q-tile tq*4+w; all waves stream the SAME K/V tiles in lockstep
// (raw s_barrier per iter, no LDS) -> L1 broadcast hits.
// ---------------------------------------------------------------------------
struct KV { u32x4 k0, k1, k2, k3, v0, v1, v2, v3; };

__global__ __launch_bounds__(256) void attn_kernel(
    const __hip_bfloat16* __restrict__ Q, const __hip_bfloat16* __restrict__ Kh,
    const __hip_bfloat16* __restrict__ Vt2, const float* __restrict__ bias2,
    __hip_bfloat16* __restrict__ Op, float* __restrict__ Mp, float* __restrict__ Lp)
{
  const int tid = threadIdx.x;
  const int lane = tid & 63, w = tid >> 6;
  const int cl = lane & 31, hi = lane >> 5;
  const int bid = blockIdx.x;
  const int g = bid % 48;            // (n,b,h) group -> fixed XCD (48 % 8 == 0)
  const int rest = bid / 48;         // 0..31
  const int sp = rest >> 3;          // split 0..3
  const int tq = rest & 7;           // q super-tile 0..7
  const int qtile = tq * 4 + w;      // 0..31
  const int h = g & 1, nb = g >> 1;
  const int b = nb & 3;
  const int qrow = nb * TT + qtile * 32;
  const int sbase = sp * (SS / NSPLIT);   // 768 keys per split

  const __hip_bfloat16* Qp = Q + (size_t)(qrow + cl) * 64 + h * 32 + hi * 8;
  u32x4 qf0 = *(const u32x4*)Qp;
  u32x4 qf1 = *(const u32x4*)(Qp + 16);

  const __hip_bfloat16* Kp = Kh + ((size_t)(nb * 2 + h) * SS + sbase) * 32;
  const __hip_bfloat16* Vp = Vt2 + (size_t)(nb * 2 + h) * SS * 32 + (size_t)sbase * 32;
  const float* Bp = bias2 + b * SS + sbase + hi * 4;

  const float scale2 = 0.17677669529663687f * 1.4426950408889634f;
  const f32x2 sc2 = {scale2, scale2};

  f32x16 ot = {};
  float m = -1e30f, lsum = 0.f;

  auto loadKV = [&](int it) {
    KV t;
    const __hip_bfloat16* kp = Kp + (size_t)it * 64 * 32;
    t.k0 = *(const u32x4*)(kp + cl * 32 + hi * 8);
    t.k1 = *(const u32x4*)(kp + cl * 32 + 16 + hi * 8);
    t.k2 = *(const u32x4*)(kp + 1024 + cl * 32 + hi * 8);
    t.k3 = *(const u32x4*)(kp + 1024 + cl * 32 + 16 + hi * 8);
    const __hip_bfloat16* vp = Vp + (size_t)it * 64 * 32;
    t.v0 = *(const u32x4*)(vp + ((0 * 2 + hi) * 32 + cl) * 8);
    t.v1 = *(const u32x4*)(vp + ((1 * 2 + hi) * 32 + cl) * 8);
    t.v2 = *(const u32x4*)(vp + ((2 * 2 + hi) * 32 + cl) * 8);
    t.v3 = *(const u32x4*)(vp + ((3 * 2 + hi) * 32 + cl) * 8);
    return t;
  };

  auto compute = [&](const KV& t, int it) {
    f32x16 pz0 = {}, pz1 = {};
    pz0 = mfma32(t.k0, qf0, pz0);
    pz0 = mfma32(t.k1, qf1, pz0);
    pz1 = mfma32(t.k2, qf0, pz1);
    pz1 = mfma32(t.k3, qf1, pz1);
    const float* bp = Bp + it * 64;
    f32x4 b4[8];
#pragma unroll
    for (int q = 0; q < 8; ++q) b4[q] = *(const f32x4*)(bp + 8 * q);
    f32x2 p2[16];
#pragma unroll
    for (int i = 0; i < 8; ++i) {
      f32x4 bq0 = b4[i >> 1];
      f32x4 bq1 = b4[4 + (i >> 1)];
      f32x2 bv0 = (i & 1) ? f32x2{bq0.z, bq0.w} : f32x2{bq0.x, bq0.y};
      f32x2 bv1 = (i & 1) ? f32x2{bq1.z, bq1.w} : f32x2{bq1.x, bq1.y};
      p2[i]     = f32x2{pz0[2*i], pz0[2*i+1]} * sc2 + bv0;
      p2[8 + i] = f32x2{pz1[2*i], pz1[2*i+1]} * sc2 + bv1;
    }
    f32x2 mx = p2[0];
#pragma unroll
    for (int i = 1; i < 16; ++i) {
      mx.x = fmaxf(mx.x, p2[i].x);
      mx.y = fmaxf(mx.y, p2[i].y);
    }
    float tm = fmaxf(mx.x, mx.y);
    tm = fmaxf(tm, __shfl_xor(tm, 32));
    if (!__all(tm - m <= 8.f)) {       // defer-max
      float mn = fmaxf(m, tm);
      float f = exp2f(m - mn);
#pragma unroll
      for (int i = 0; i < 16; ++i) ot[i] *= f;
      lsum *= f;
      m = mn;
    }
    const f32x2 m2 = {m, m};
    f32x2 s2 = {0.f, 0.f};
#pragma unroll
    for (int i = 0; i < 16; ++i) {
      f32x2 d = p2[i] - m2;
      f32x2 e = {exp2f(d.x), exp2f(d.y)};
      p2[i] = e;
      s2 += e;
    }
    float ts = s2.x + s2.y;
    ts += __shfl_xor(ts, 32);
    lsum += ts;
    // P -> bf16 B-frags via permlane32_swap
    uint cv[16];
#pragma unroll
    for (int i = 0; i < 16; ++i) cv[i] = pkbf(p2[i].x, p2[i].y);
    u32x4 pf0, pf1, pf2, pf3;
    {
      uint x0, y0, x1, y1;
      plswap(cv[0], cv[2],  x0, y0); plswap(cv[1], cv[3],  x1, y1);
      pf0 = u32x4{x0, x1, y0, y1};
      plswap(cv[4], cv[6],  x0, y0); plswap(cv[5], cv[7],  x1, y1);
      pf1 = u32x4{x0, x1, y0, y1};
      plswap(cv[8], cv[10], x0, y0); plswap(cv[9], cv[11], x1, y1);
      pf2 = u32x4{x0, x1, y0, y1};
      plswap(cv[12], cv[14], x0, y0); plswap(cv[13], cv[15], x1, y1);
      pf3 = u32x4{x0, x1, y0, y1};
    }
    ot = mfma32(t.v0, pf0, ot);
    ot = mfma32(t.v1, pf1, ot);
    ot = mfma32(t.v2, pf2, ot);
    ot = mfma32(t.v3, pf3, ot);
  };

  KV cur = loadKV(0);
#pragma unroll 1
  for (int it = 0; it < 12; ++it) {
    KV nxt = loadKV(it + 1 < 12 ? it + 1 : 11);
    compute(cur, it);
    cur = nxt;
    __builtin_amdgcn_s_barrier();   // keep the 4 waves' K/V streams in lockstep (L1 reuse)
  }

  // store unnormalized O^T partial (bf16) + m/l
  __hip_bfloat16* op = Op + ((size_t)sp * NROW + qrow + cl) * 64 + h * 32 + 4 * hi;
#pragma unroll
  for (int k = 0; k < 4; ++k) {
    uint2 wv = {pkbf(ot[4*k], ot[4*k+1]), pkbf(ot[4*k+2], ot[4*k+3])};
    *(uint2*)(op + 8 * k) = wv;
  }
  if (lane < 32) {
    int mi = ((sp * 24 + nb) * 2 + h) * TT + qtile * 32 + cl;
    Mp[mi] = m;
    Lp[mi] = lsum;
  }
}

// ---------------------------------------------------------------------------
// Fused split-combine + out-projection (MFMA) + residual + LayerNorm.
// Block 256 = 4 waves, 32 rows; wave w owns cols [w*192, +192).
// ---------------------------------------------------------------------------
__global__ __launch_bounds__(256) void oproj_ln_kernel(
    const float* __restrict__ x, const __hip_bfloat16* __restrict__ Op,
    const float* __restrict__ Mp, const float* __restrict__ Lp,
    const __hip_bfloat16* __restrict__ Bo, const float* __restrict__ gamma,
    const float* __restrict__ beta, float* __restrict__ out)
{
  __shared__ float red[4][32][2];
  __shared__ float redf[32][2];
  const int tid = threadIdx.x;
  const int lane = tid & 63, w = tid >> 6;
  const int cl = lane & 31, hi = lane >> 5;
  const int row0 = blockIdx.x * 32;
  const int n = row0 >> 12;
  const int nb = row0 >> 10;
  const int trow = (row0 & 1023) + cl;
  const int MLS = 24 * 2 * TT;

  // combine weights per head
  float wsp[2][NSPLIT];
#pragma unroll
  for (int h = 0; h < 2; ++h) {
    int mi = (nb * 2 + h) * TT + trow;
    float mv[NSPLIT], lv[NSPLIT];
#pragma unroll
    for (int sp = 0; sp < NSPLIT; ++sp) { mv[sp] = Mp[mi + sp * MLS]; lv[sp] = Lp[mi + sp * MLS]; }
    float ms = mv[0];
#pragma unroll
    for (int sp = 1; sp < NSPLIT; ++sp) ms = fmaxf(ms, mv[sp]);
    float den = 0.f;
#pragma unroll
    for (int sp = 0; sp < NSPLIT; ++sp) { wsp[h][sp] = exp2f(mv[sp] - ms); den = fmaf(lv[sp], wsp[h][sp], den); }
    float inv = 1.0f / den;
#pragma unroll
    for (int sp = 0; sp < NSPLIT; ++sp) wsp[h][sp] *= inv;
  }

  // A-frags: combine partials
  u32x4 af[4];
#pragma unroll
  for (int ks = 0; ks < 4; ++ks) {
    int h = ks >> 1;
    size_t off = (size_t)(row0 + cl) * 64 + ks * 16 + hi * 8;
    f32x2 s0 = {}, s1 = {}, s2 = {}, s3 = {};
#pragma unroll
    for (int sp = 0; sp < NSPLIT; ++sp) {
      u32x4 v = *(const u32x4*)(Op + (size_t)sp * NROW * 64 + off);
      float wv = wsp[h][sp];
      s0 += f32x2{b2f(v[0] & 0xffffu), b2f(v[0] >> 16)} * wv;
      s1 += f32x2{b2f(v[1] & 0xffffu), b2f(v[1] >> 16)} * wv;
      s2 += f32x2{b2f(v[2] & 0xffffu), b2f(v[2] >> 16)} * wv;
      s3 += f32x2{b2f(v[3] & 0xffffu), b2f(v[3] >> 16)} * wv;
    }
    af[ks] = u32x4{pkbf(s0.x, s0.y), pkbf(s1.x, s1.y), pkbf(s2.x, s2.y), pkbf(s3.x, s3.y)};
  }

  const __hip_bfloat16* Bp = Bo + ((size_t)n * 768 + w * 192 + cl) * 64 + hi * 8;
  f32x16 acc[6] = {};
#pragma unroll
  for (int ks = 0; ks < 4; ++ks) {
#pragma unroll
    for (int t = 0; t < 6; ++t) {
      u32x4 bb = *(const u32x4*)(Bp + (size_t)(t * 32) * 64 + ks * 16);
      acc[t] = mfma32(af[ks], bb, acc[t]);
    }
  }

  float s1[16], s2[16];
#pragma unroll
  for (int r = 0; r < 16; ++r) { s1[r] = 0.f; s2[r] = 0.f; }
#pragma unroll
  for (int t = 0; t < 6; ++t) {
#pragma unroll
    for (int r = 0; r < 16; ++r) {
      int R = (r & 3) + 8 * (r >> 2) + 4 * hi;
      int col = w * 192 + t * 32 + cl;
      float y = acc[t][r] + x[(size_t)(row0 + R) * 768 + col];
      acc[t][r] = y;
      s1[r] += y;
      s2[r] = fmaf(y, y, s2[r]);
    }
  }
#pragma unroll
  for (int r = 0; r < 16; ++r) {
#pragma unroll
    for (int off = 1; off < 32; off <<= 1) {
      s1[r] += __shfl_xor(s1[r], off);
      s2[r] += __shfl_xor(s2[r], off);
    }
  }
  if (cl == 0) {
#pragma unroll
    for (int r = 0; r < 16; ++r) {
      int R = (r & 3) + 8 * (r >> 2) + 4 * hi;
      red[w][R][0] = s1[r];
      red[w][R][1] = s2[r];
    }
  }
  __syncthreads();
  if (tid < 64) {
    int R = tid & 31, st = tid >> 5;
    redf[R][st] = red[0][R][st] + red[1][R][st] + red[2][R][st] + red[3][R][st];
  }
  __syncthreads();

  float gv[6], bv[6];
#pragma unroll
  for (int t = 0; t < 6; ++t) {
    int col = w * 192 + t * 32 + cl;
    gv[t] = gamma[n * 768 + col];
    bv[t] = beta[n * 768 + col];
  }
#pragma unroll
  for (int r = 0; r < 16; ++r) {
    int R = (r & 3) + 8 * (r >> 2) + 4 * hi;
    float mu = redf[R][0] * (1.0f / 768.0f);
    float var = redf[R][1] * (1.0f / 768.0f) - mu * mu;
    float rs = rsqrtf(var + LNEPS);
#pragma unroll
    for (int t = 0; t < 6; ++t) {
      int col = w * 192 + t * 32 + cl;
      out[(size_t)(row0 + R) * 768 + col] = (acc[t][r] - mu) * rs * gv[t] + bv[t];
    }
  }
}

// ---------------------------------------------------------------------------
extern "C" void kernel_launch(void* const* d_in, const int* in_sizes, int n_in,
                              void* d_out, int out_size, void* d_ws, size_t ws_size,
                              hipStream_t stream) {
  const float* x     = (const float*)d_in[0];
  const float* hist  = (const float*)d_in[1];
  const int*   mask  = (const int*)d_in[2];
  const float* Wq    = (const float*)d_in[3];
  const float* Wk    = (const float*)d_in[4];
  const float* Wv    = (const float*)d_in[5];
  const float* Wo    = (const float*)d_in[6];
  const float* gamma = (const float*)d_in[7];
  const float* beta  = (const float*)d_in[8];
  float* out = (float*)d_out;

  char* ws = (char*)d_ws;
  __hip_bfloat16* Qb  = (__hip_bfloat16*)ws;  ws += (size_t)NROW * II * 2;
  __hip_bfloat16* Kh  = (__hip_bfloat16*)ws;  ws += (size_t)NKVROW * II * 2;
  __hip_bfloat16* Vt2 = (__hip_bfloat16*)ws;  ws += (size_t)NKVROW * II * 2;
  __hip_bfloat16* Op  = (__hip_bfloat16*)ws;  ws += (size_t)NSPLIT * NROW * II * 2;
  float* Mp           = (float*)ws;           ws += (size_t)NSPLIT * 24 * 2 * TT * 4;
  float* Lp           = (float*)ws;           ws += (size_t)NSPLIT * 24 * 2 * TT * 4;
  __hip_bfloat16* Bkvf = (__hip_bfloat16*)ws; ws += (size_t)96 * 128 * 8 * 2;
  __hip_bfloat16* Bqf  = (__hip_bfloat16*)ws; ws += (size_t)NDOM * 96 * 64 * 8 * 2;
  __hip_bfloat16* Bo  = (__hip_bfloat16*)ws;  ws += (size_t)NDOM * 768 * 64 * 2;
  float* bias2        = (float*)ws;           ws += (size_t)BB * SS * 4;

  const int PREP_N = 96*128*8 + NDOM*96*64*8 + NDOM*768*64 + BB*SS;
  prep_kernel<<<(PREP_N + 255) / 256, 256, 0, stream>>>(mask, Wk, Wv, Wq, Wo, Bkvf, Bqf, Bo, bias2);
  qkv_gemm_kernel<<<NKVB + NQB, 256, 0, stream>>>(x, hist, Bkvf, Bqf, Qb, Kh, Vt2);
  attn_kernel<<<48 * 8 * NSPLIT, 256, 0, stream>>>(Qb, Kh, Vt2, bias2, Op, Mp, Lp);
  oproj_ln_kernel<<<NROW / 32, 256, 0, stream>>>(x, Op, Mp, Lp, Bo, gamma, beta, out);
}